// Round 4
// baseline (894.833 us; speedup 1.0000x reference)
//
#include <hip/hip_runtime.h>
#include <hip/hip_bf16.h>

#define NN 100000
#define EE 800000
#define THRV 0.1f
#define DELTA 0.008f
#define EPSV 1e-8f

#define ATOMIC_ADD_F32 unsafeAtomicAdd

__device__ inline unsigned short f2bf(float f) {
    unsigned int u = __float_as_uint(f);
    u += 0x7fffu + ((u >> 16) & 1u);
    return (unsigned short)(u >> 16);
}

__device__ inline void unpack2(unsigned int u, float& lo, float& hi) {
    lo = __uint_as_float(u << 16);
    hi = __uint_as_float(u & 0xffff0000u);
}

// ================= edge sort (counting sort by destination row) =================

__global__ void hist_k(const int* __restrict__ r1, const int* __restrict__ r2,
                       int* __restrict__ hist) {
    int e = blockIdx.x * 256 + threadIdx.x;          // 0..2E
    if (e < EE) atomicAdd(&hist[r1[e]], 1);
    else        atomicAdd(&hist[NN + r2[e - EE]], 1);
}

__global__ __launch_bounds__(512) void scan1_k(const int* __restrict__ in,
                                               int* __restrict__ out,
                                               int* __restrict__ partials, int n) {
    __shared__ int a[1024], b[1024];
    int t = threadIdx.x;
    int base = blockIdx.x * 1024;
    a[t]       = (base + t       < n) ? in[base + t]       : 0;
    a[t + 512] = (base + t + 512 < n) ? in[base + t + 512] : 0;
    __syncthreads();
    int* src = a; int* dst = b;
    for (int off = 1; off < 1024; off <<= 1) {
        #pragma unroll
        for (int q = 0; q < 2; q++) {
            int i = t + q * 512;
            int v = src[i];
            if (i >= off) v += src[i - off];
            dst[i] = v;
        }
        __syncthreads();
        int* tmp = src; src = dst; dst = tmp;
    }
    for (int q = 0; q < 2; q++) {
        int i = t + q * 512;
        if (base + i < n) out[base + i] = i ? src[i - 1] : 0;
    }
    if (t == 0) partials[blockIdx.x] = src[1023];
}

__global__ __launch_bounds__(256) void scan2_k(int* __restrict__ partials, int m) {
    __shared__ int a[256], b[256];
    int t = threadIdx.x;
    a[t] = (t < m) ? partials[t] : 0;
    __syncthreads();
    int* src = a; int* dst = b;
    for (int off = 1; off < 256; off <<= 1) {
        int v = src[t];
        if (t >= off) v += src[t - off];
        dst[t] = v;
        __syncthreads();
        int* tmp = src; src = dst; dst = tmp;
    }
    if (t < m) partials[t] = t ? src[t - 1] : 0;
}

__global__ void scan3_k(int* __restrict__ start, int* __restrict__ next,
                        const int* __restrict__ partials, int n, int total) {
    int i = blockIdx.x * 256 + threadIdx.x;
    if (i < n) {
        int v = start[i] + partials[i >> 10];
        start[i] = v;
        next[i] = v;
    }
    if (i == 0) start[n] = total;
}

__global__ void scatter_k(const int* __restrict__ r1, const int* __restrict__ c1,
                          const int* __restrict__ r2, const int* __restrict__ c2,
                          int* __restrict__ next, int* __restrict__ srow,
                          int* __restrict__ scol) {
    int e = blockIdx.x * 256 + threadIdx.x;
    int gr, c;
    if (e < EE) { gr = r1[e]; c = c1[e]; }
    else        { gr = NN + r2[e - EE]; c = c2[e - EE]; }
    int pos = atomicAdd(&next[gr], 1);
    srow[pos] = gr;
    scol[pos] = c;
}

// ================= normalize x -> bf16 rows + norms + degL1=1 =================

__global__ __launch_bounds__(256) void normalize_k(const float* __restrict__ x,
                                                   unsigned short* __restrict__ xnb,
                                                   float* __restrict__ norms_x,
                                                   float* __restrict__ degL1) {
    int node = blockIdx.x * 4 + (threadIdx.x >> 6);
    int lane = threadIdx.x & 63;
    float2 v = reinterpret_cast<const float2*>(x)[(size_t)node * 64 + lane];
    float ss = v.x * v.x + v.y * v.y;
    #pragma unroll
    for (int off = 32; off; off >>= 1) ss += __shfl_xor(ss, off);
    float norm = fmaxf(sqrtf(ss), EPSV);
    float inv = 1.0f / norm;
    ushort2 o;
    o.x = f2bf(v.x * inv);
    o.y = f2bf(v.y * inv);
    reinterpret_cast<ushort2*>(xnb)[(size_t)node * 64 + lane] = o;
    if (lane == 0) {
        norms_x[node] = norm;
        degL1[node] = 1.0f;
        degL1[node + NN] = 1.0f;
    }
}

// ================= pass-1 edge sim: sorted, bf16, 2 edges/wave, f32 fallback ====

__global__ __launch_bounds__(256) void edge_sim1_k(
        const unsigned short* __restrict__ xnb, const float* __restrict__ x,
        const float* __restrict__ norms_x,
        const int* __restrict__ srow, const int* __restrict__ scol,
        float* __restrict__ ews, float* __restrict__ degL1) {
    int tid = threadIdx.x;
    int lane = tid & 63;
    int e = blockIdx.x * 8 + ((tid >> 6) << 1) + (lane >> 5);   // 2 edges per wave
    int gr = srow[e];
    int cnode = scol[e];
    int rnode = (gr < NN) ? gr : gr - NN;
    int role = (lane >> 4) & 1;
    int l16 = lane & 15;
    int node = role ? cnode : rnode;
    uint4 v = *reinterpret_cast<const uint4*>(xnb + (size_t)node * 128 + l16 * 8);
    uint4 p;
    p.x = (unsigned)__shfl_xor((int)v.x, 16);
    p.y = (unsigned)__shfl_xor((int)v.y, 16);
    p.z = (unsigned)__shfl_xor((int)v.z, 16);
    p.w = (unsigned)__shfl_xor((int)v.w, 16);
    float s = 0.f, lv, hv, lp, hp;
    unpack2(v.x, lv, hv); unpack2(p.x, lp, hp); s += lv * lp + hv * hp;
    unpack2(v.y, lv, hv); unpack2(p.y, lp, hp); s += lv * lp + hv * hp;
    unpack2(v.z, lv, hv); unpack2(p.z, lp, hp); s += lv * lp + hv * hp;
    unpack2(v.w, lv, hv); unpack2(p.w, lp, hp); s += lv * lp + hv * hp;
    #pragma unroll
    for (int off = 1; off < 16; off <<= 1) s += __shfl_xor(s, off);
    float sim = s;
    if (fabsf(sim - THRV) <= DELTA) {
        int j = lane & 31;
        const float2* xr = reinterpret_cast<const float2*>(x) + (size_t)rnode * 64;
        const float2* xc = reinterpret_cast<const float2*>(x) + (size_t)cnode * 64;
        float2 a0 = xr[j], a1 = xr[j + 32];
        float2 b0 = xc[j], b1 = xc[j + 32];
        float d = a0.x * b0.x + a0.y * b0.y + a1.x * b1.x + a1.y * b1.y;
        #pragma unroll
        for (int off = 1; off < 32; off <<= 1) d += __shfl_xor(d, off);
        sim = d / (norms_x[rnode] * norms_x[cnode]);
    }
    float w = (sim >= THRV) ? sim : 0.0f;
    if ((lane & 31) == 0) {
        ews[e] = w;
        if (w != 0.0f) ATOMIC_ADD_F32(&degL1[gr], w);
    }
}

// ================= pass-2 edge sim: sorted, f32, alive-only =================

__global__ __launch_bounds__(256) void edge_sim2_k(
        const float* __restrict__ agg, const float* __restrict__ norms_l2,
        const int* __restrict__ srow, const int* __restrict__ scol,
        float* __restrict__ ews, float* __restrict__ degL2) {
    int e = blockIdx.x * 4 + (threadIdx.x >> 6);
    int lane = threadIdx.x & 63;
    if (ews[e] == 0.0f) return;
    int gr = srow[e];
    int cg = ((e < EE) ? 0 : NN) + scol[e];
    float2 a = reinterpret_cast<const float2*>(agg)[(size_t)gr * 64 + lane];
    float2 b = reinterpret_cast<const float2*>(agg)[(size_t)cg * 64 + lane];
    float d = a.x * b.x + a.y * b.y;
    #pragma unroll
    for (int off = 32; off; off >>= 1) d += __shfl_xor(d, off);
    if (lane == 0) {
        float sim = d / (norms_l2[gr] * norms_l2[cg]);
        float w = (sim >= THRV) ? sim : 0.0f;
        ews[e] = w;
        if (w != 0.0f) ATOMIC_ADD_F32(&degL2[gr], w);
    }
}

// ================= GEMM: [n,128] x [128,128] -> [n,128] =================

__global__ __launch_bounds__(256) void gemm_nh_k(const float* __restrict__ A,
                                                 const float* __restrict__ W,
                                                 float* __restrict__ C, int n) {
    __shared__ float Ws[64 * 128];
    __shared__ float Xs[32 * 64];
    int tid = threadIdx.x;
    int row0 = blockIdx.x * 32;
    int cg = tid & 31;
    int rl = tid >> 5;
    float4 acc[4];
    #pragma unroll
    for (int i = 0; i < 4; i++) acc[i] = make_float4(0.f, 0.f, 0.f, 0.f);

    for (int kt = 0; kt < 2; kt++) {
        const float4* Wg = reinterpret_cast<const float4*>(W + kt * 64 * 128);
        float4* Ws4 = reinterpret_cast<float4*>(Ws);
        #pragma unroll
        for (int i = 0; i < 8; i++) Ws4[tid + 256 * i] = Wg[tid + 256 * i];
        float4* Xs4 = reinterpret_cast<float4*>(Xs);
        #pragma unroll
        for (int i = 0; i < 2; i++) {
            int idx = tid + 256 * i;
            int rr = idx >> 4, kq = idx & 15;
            int grow = row0 + rr; if (grow >= n) grow = n - 1;
            Xs4[idx] = reinterpret_cast<const float4*>(A + (size_t)grow * 128 + kt * 64)[kq];
        }
        __syncthreads();
        for (int k = 0; k < 64; k++) {
            float4 wv = reinterpret_cast<const float4*>(Ws + k * 128)[cg];
            #pragma unroll
            for (int r4 = 0; r4 < 4; r4++) {
                float xv = Xs[(rl + 8 * r4) * 64 + k];
                acc[r4].x += xv * wv.x; acc[r4].y += xv * wv.y;
                acc[r4].z += xv * wv.z; acc[r4].w += xv * wv.w;
            }
        }
        __syncthreads();
    }
    #pragma unroll
    for (int r4 = 0; r4 < 4; r4++) {
        int grow = row0 + rl + 8 * r4;
        if (grow < n) reinterpret_cast<float4*>(C + (size_t)grow * 128)[cg] = acc[r4];
    }
}

// ================= GEMM: [n,128] x [128,40] -> [n,40] =================

__global__ __launch_bounds__(256) void gemm_nc_k(const float* __restrict__ A,
                                                 const float* __restrict__ W,
                                                 float* __restrict__ C, int n) {
    __shared__ float Ws[128 * 40];
    __shared__ float Xs[64 * 130];
    int tid = threadIdx.x;
    int row0 = blockIdx.x * 64;
    for (int i = tid; i < 128 * 40; i += 256) Ws[i] = W[i];
    #pragma unroll
    for (int i = 0; i < 8; i++) {
        int idx = tid + 256 * i;
        int rr = idx >> 5, kq = idx & 31;
        int grow = row0 + rr; if (grow >= n) grow = n - 1;
        float4 v = reinterpret_cast<const float4*>(A + (size_t)grow * 128)[kq];
        float* dst = &Xs[rr * 130 + kq * 4];
        dst[0] = v.x; dst[1] = v.y; dst[2] = v.z; dst[3] = v.w;
    }
    __syncthreads();
    int c5 = tid & 7;
    int r  = tid >> 3;
    float acc0[5] = {0, 0, 0, 0, 0}, acc1[5] = {0, 0, 0, 0, 0};
    for (int k = 0; k < 128; k++) {
        float x0 = Xs[r * 130 + k], x1 = Xs[(r + 32) * 130 + k];
        #pragma unroll
        for (int c = 0; c < 5; c++) {
            float wv = Ws[k * 40 + c5 * 5 + c];
            acc0[c] += x0 * wv; acc1[c] += x1 * wv;
        }
    }
    int g0 = row0 + r, g1 = row0 + r + 32;
    if (g0 < n) {
        for (int c = 0; c < 5; c++) C[(size_t)g0 * 40 + c5 * 5 + c] = acc0[c];
    }
    if (g1 < n) {
        for (int c = 0; c < 5; c++) C[(size_t)g1 * 40 + c5 * 5 + c] = acc1[c];
    }
}

// ========= CSR aggregate D=128, fused finish + relu + norm + degL2 init =========
// one wave per destination row (2NN rows)

__global__ __launch_bounds__(256) void agg128_fused_k(
        const float* __restrict__ h, const int* __restrict__ start,
        const int* __restrict__ scol, const float* __restrict__ ews,
        const float* __restrict__ degL1, const float* __restrict__ bias,
        float* __restrict__ agg, float* __restrict__ norms_l2,
        float* __restrict__ degL2) {
    int gr = blockIdx.x * 4 + (threadIdx.x >> 6);
    int lane = threadIdx.x & 63;
    int set_base = (gr < NN) ? 0 : NN;
    int rnode = gr - set_base;
    int j0 = start[gr], j1 = start[gr + 1];
    float2 acc = make_float2(0.f, 0.f);
    for (int j = j0; j < j1; j++) {
        float w = ews[j];
        if (w == 0.0f) continue;
        int c = scol[j];
        float nv = w * rsqrtf(degL1[set_base + c]);
        float2 hv = reinterpret_cast<const float2*>(h)[(size_t)c * 64 + lane];
        acc.x += hv.x * nv;
        acc.y += hv.y * nv;
    }
    float dr = rsqrtf(degL1[gr]);
    float2 hs = reinterpret_cast<const float2*>(h)[(size_t)rnode * 64 + lane];
    float2 bb = reinterpret_cast<const float2*>(bias)[lane];
    float vx = fmaxf(acc.x * dr + hs.x * dr * dr + bb.x, 0.0f);
    float vy = fmaxf(acc.y * dr + hs.y * dr * dr + bb.y, 0.0f);
    reinterpret_cast<float2*>(agg)[(size_t)gr * 64 + lane] = make_float2(vx, vy);
    float ss = vx * vx + vy * vy;
    #pragma unroll
    for (int off = 32; off; off >>= 1) ss += __shfl_xor(ss, off);
    if (lane == 0) {
        norms_l2[gr] = fmaxf(sqrtf(ss), EPSV);
        degL2[gr] = 1.0f;
    }
}

// ========= CSR aggregate D=40, fused finish =========
// one wave per destination row (lanes 0..39 active)

__global__ __launch_bounds__(256) void agg40_fused_k(
        const float* __restrict__ h2, const int* __restrict__ start,
        const int* __restrict__ scol, const float* __restrict__ ews,
        const float* __restrict__ degL2, const float* __restrict__ bias,
        float* __restrict__ aggy) {
    int gr = blockIdx.x * 4 + (threadIdx.x >> 6);
    int lane = threadIdx.x & 63;
    int set_base = (gr < NN) ? 0 : NN;
    int j0 = start[gr], j1 = start[gr + 1];
    bool act = lane < 40;
    float acc = 0.f;
    for (int j = j0; j < j1; j++) {
        float w = ews[j];
        if (w == 0.0f) continue;
        int c = set_base + scol[j];
        float nv = w * rsqrtf(degL2[c]);
        if (act) acc += h2[(size_t)c * 40 + lane] * nv;
    }
    if (act) {
        float dr = rsqrtf(degL2[gr]);
        float self = h2[(size_t)gr * 40 + lane];
        aggy[(size_t)gr * 40 + lane] = acc * dr + self * dr * dr + bias[lane];
    }
}

// ================= fusion + log_softmax =================

__global__ __launch_bounds__(256) void fusion_k(const float* __restrict__ y1,
                                                const float* __restrict__ y2,
                                                const float* __restrict__ W1,
                                                const float* __restrict__ b1,
                                                const float* __restrict__ W2,
                                                float* __restrict__ out, int n) {
    __shared__ float W1s[40 * 40];
    __shared__ float b1s[40];
    __shared__ float W2s[40];
    int tid = threadIdx.x;
    for (int i = tid; i < 1600; i += 256) W1s[i] = W1[i];
    if (tid < 40) { b1s[tid] = b1[tid]; W2s[tid] = W2[tid]; }
    __syncthreads();
    int i = blockIdx.x * 256 + tid;
    if (i >= n) return;
    float z1[40], z2[40];
    const float4* y14 = reinterpret_cast<const float4*>(y1 + (size_t)i * 40);
    const float4* y24 = reinterpret_cast<const float4*>(y2 + (size_t)i * 40);
    #pragma unroll
    for (int q = 0; q < 10; q++) {
        float4 a = y14[q], b = y24[q];
        z1[4 * q] = a.x; z1[4 * q + 1] = a.y; z1[4 * q + 2] = a.z; z1[4 * q + 3] = a.w;
        z2[4 * q] = b.x; z2[4 * q + 1] = b.y; z2[4 * q + 2] = b.z; z2[4 * q + 3] = b.w;
    }
    float w1 = 0.f, w2 = 0.f;
    for (int c = 0; c < 40; c++) {
        float s1 = b1s[c], s2 = b1s[c];
        for (int j = 0; j < 40; j++) {
            float ww = W1s[j * 40 + c];
            s1 += z1[j] * ww; s2 += z2[j] * ww;
        }
        float wa = W2s[c];
        w1 += tanhf(s1) * wa; w2 += tanhf(s2) * wa;
    }
    float m = fmaxf(w1, w2);
    float e1 = expf(w1 - m), e2 = expf(w2 - m);
    float inv = 1.0f / (e1 + e2);
    float be1 = e1 * inv, be2 = e2 * inv;
    float fu[40];
    float mx = -1e30f;
    #pragma unroll
    for (int c = 0; c < 40; c++) {
        fu[c] = be1 * z1[c] + be2 * z2[c];
        mx = fmaxf(mx, fu[c]);
    }
    float se = 0.f;
    #pragma unroll
    for (int c = 0; c < 40; c++) se += expf(fu[c] - mx);
    float ls = logf(se);
    float4* o4 = reinterpret_cast<float4*>(out + (size_t)i * 40);
    #pragma unroll
    for (int q = 0; q < 10; q++) {
        float4 v;
        v.x = fu[4 * q] - mx - ls; v.y = fu[4 * q + 1] - mx - ls;
        v.z = fu[4 * q + 2] - mx - ls; v.w = fu[4 * q + 3] - mx - ls;
        o4[q] = v;
    }
}

// ================= host =================

extern "C" void kernel_launch(void* const* d_in, const int* in_sizes, int n_in,
                              void* d_out, int out_size, void* d_ws, size_t ws_size,
                              hipStream_t stream) {
    (void)in_sizes; (void)n_in; (void)out_size; (void)ws_size;
    const float* x   = (const float*)d_in[0];
    const float* Wg1 = (const float*)d_in[1];
    const float* bg1 = (const float*)d_in[2];
    const float* Wg2 = (const float*)d_in[3];
    const float* bg2 = (const float*)d_in[4];
    const float* Wa1 = (const float*)d_in[5];
    const float* ba1 = (const float*)d_in[6];
    const float* Wa2 = (const float*)d_in[7];
    const int* ei1 = (const int*)d_in[8];
    const int* ei2 = (const int*)d_in[9];
    const int *r1 = ei1, *c1 = ei1 + EE;
    const int *r2 = ei2, *c2 = ei2 + EE;
    float* out = (float*)d_out;

    // ---- workspace carve (floats) ----
    float* ws = (float*)d_ws;
    float* norms_x  = ws;  ws += NN;
    float* norms_l2 = ws;  ws += 2 * NN;
    float* degL1    = ws;  ws += 2 * NN;
    float* degL2    = ws;  ws += 2 * NN;
    int*   start    = (int*)ws;  ws += 2 * NN + 8;
    int*   next     = (int*)ws;  ws += 2 * NN;
    int*   partials = (int*)ws;  ws += 512;
    int*   srow     = (int*)ws;  ws += 2 * EE;
    int*   scol     = (int*)ws;  ws += 2 * EE;
    float* ews      = ws;  ws += 2 * EE;
    float* h        = ws;  ws += (size_t)NN * 128;   // h2 (2NN x 40) overlays
    float* agg      = ws;  ws += (size_t)2 * NN * 128; // xnb overlays head; aggy overlays after gemm_nc
    unsigned short* xnb = (unsigned short*)agg;
    float* h2   = h;
    float* aggy = agg;

    const int twoN = 2 * NN;
    const int twoE = 2 * EE;
    const int scan_blocks = (twoN + 1023) / 1024;    // 196

    // ---- edge sort ----
    (void)hipMemsetAsync(next, 0, sizeof(int) * twoN, stream);
    hist_k<<<twoE / 256, 256, 0, stream>>>(r1, r2, next);
    normalize_k<<<NN / 4, 256, 0, stream>>>(x, xnb, norms_x, degL1);
    scan1_k<<<scan_blocks, 512, 0, stream>>>(next, start, partials, twoN);
    scan2_k<<<1, 256, 0, stream>>>(partials, scan_blocks);
    scan3_k<<<(twoN + 255) / 256, 256, 0, stream>>>(start, next, partials, twoN, twoE);
    scatter_k<<<twoE / 256, 256, 0, stream>>>(r1, c1, r2, c2, next, srow, scol);

    // ---- layer 1 ----
    edge_sim1_k<<<twoE / 8, 256, 0, stream>>>(xnb, x, norms_x, srow, scol, ews, degL1);
    gemm_nh_k<<<NN / 32, 256, 0, stream>>>(x, Wg1, h, NN);
    agg128_fused_k<<<twoN / 4, 256, 0, stream>>>(h, start, scol, ews, degL1, bg1,
                                                 agg, norms_l2, degL2);

    // ---- layer 2 ----
    edge_sim2_k<<<twoE / 4, 256, 0, stream>>>(agg, norms_l2, srow, scol, ews, degL2);
    gemm_nc_k<<<twoN / 64, 256, 0, stream>>>(agg, Wg2, h2, twoN);
    agg40_fused_k<<<twoN / 4, 256, 0, stream>>>(h2, start, scol, ews, degL2, bg2, aggy);

    // ---- fusion + log_softmax ----
    fusion_k<<<(NN + 255) / 256, 256, 0, stream>>>(aggy, aggy + (size_t)NN * 40,
                                                   Wa1, ba1, Wa2, out, NN);
}

// Round 5
// 554.378 us; speedup vs baseline: 1.6141x; 1.6141x over previous
//
#include <hip/hip_runtime.h>
#include <hip/hip_bf16.h>

#define NN 100000
#define EE 800000
#define THRV 0.1f
#define DELTA 0.008f
#define EPSV 1e-8f

#define ATOMIC_ADD_F32 unsafeAtomicAdd

__device__ inline unsigned short f2bf(float f) {
    unsigned int u = __float_as_uint(f);
    u += 0x7fffu + ((u >> 16) & 1u);
    return (unsigned short)(u >> 16);
}

__device__ inline void unpack2(unsigned int u, float& lo, float& hi) {
    lo = __uint_as_float(u << 16);
    hi = __uint_as_float(u & 0xffff0000u);
}

// ================= normalize x -> bf16 rows + norms + degL1=1 =================

__global__ __launch_bounds__(256) void normalize_k(const float* __restrict__ x,
                                                   unsigned short* __restrict__ xnb,
                                                   float* __restrict__ norms_x,
                                                   float* __restrict__ degL1) {
    int node = blockIdx.x * 4 + (threadIdx.x >> 6);
    int lane = threadIdx.x & 63;
    float2 v = reinterpret_cast<const float2*>(x)[(size_t)node * 64 + lane];
    float ss = v.x * v.x + v.y * v.y;
    #pragma unroll
    for (int off = 32; off; off >>= 1) ss += __shfl_xor(ss, off);
    float norm = fmaxf(sqrtf(ss), EPSV);
    float inv = 1.0f / norm;
    ushort2 o;
    o.x = f2bf(v.x * inv);
    o.y = f2bf(v.y * inv);
    reinterpret_cast<ushort2*>(xnb)[(size_t)node * 64 + lane] = o;
    if (lane == 0) {
        norms_x[node] = norm;
        degL1[node] = 1.0f;
        degL1[node + NN] = 1.0f;
    }
}

// ===== pass-1 edge sim: original order, bf16, 2 edges/wave, f32 fallback =====
// writes ews (coalesced), degL1 weighted atomic, cnt alive-count atomic

__global__ __launch_bounds__(256) void edge_sim1_k(
        const unsigned short* __restrict__ xnb, const float* __restrict__ x,
        const float* __restrict__ norms_x,
        const int* __restrict__ r1, const int* __restrict__ c1,
        const int* __restrict__ r2, const int* __restrict__ c2,
        float* __restrict__ ews, float* __restrict__ degL1,
        int* __restrict__ cnt) {
    int tid = threadIdx.x;
    int lane = tid & 63;
    int e = blockIdx.x * 8 + ((tid >> 6) << 1) + (lane >> 5);   // 0..2E
    int rnode, cnode, gr;
    if (e < EE) { rnode = r1[e]; cnode = c1[e]; gr = rnode; }
    else { int ee = e - EE; rnode = r2[ee]; cnode = c2[ee]; gr = NN + rnode; }
    int role = (lane >> 4) & 1;
    int l16 = lane & 15;
    int node = role ? cnode : rnode;
    uint4 v = *reinterpret_cast<const uint4*>(xnb + (size_t)node * 128 + l16 * 8);
    uint4 p;
    p.x = (unsigned)__shfl_xor((int)v.x, 16);
    p.y = (unsigned)__shfl_xor((int)v.y, 16);
    p.z = (unsigned)__shfl_xor((int)v.z, 16);
    p.w = (unsigned)__shfl_xor((int)v.w, 16);
    float s = 0.f, lv, hv, lp, hp;
    unpack2(v.x, lv, hv); unpack2(p.x, lp, hp); s += lv * lp + hv * hp;
    unpack2(v.y, lv, hv); unpack2(p.y, lp, hp); s += lv * lp + hv * hp;
    unpack2(v.z, lv, hv); unpack2(p.z, lp, hp); s += lv * lp + hv * hp;
    unpack2(v.w, lv, hv); unpack2(p.w, lp, hp); s += lv * lp + hv * hp;
    #pragma unroll
    for (int off = 1; off < 16; off <<= 1) s += __shfl_xor(s, off);
    float sim = s;
    if (fabsf(sim - THRV) <= DELTA) {
        int j = lane & 31;
        const float2* xr = reinterpret_cast<const float2*>(x) + (size_t)rnode * 64;
        const float2* xc = reinterpret_cast<const float2*>(x) + (size_t)cnode * 64;
        float2 a0 = xr[j], a1 = xr[j + 32];
        float2 b0 = xc[j], b1 = xc[j + 32];
        float d = a0.x * b0.x + a0.y * b0.y + a1.x * b1.x + a1.y * b1.y;
        #pragma unroll
        for (int off = 1; off < 32; off <<= 1) d += __shfl_xor(d, off);
        sim = d / (norms_x[rnode] * norms_x[cnode]);
    }
    float w = (sim >= THRV) ? sim : 0.0f;
    if ((lane & 31) == 0) {
        ews[e] = w;
        if (w != 0.0f) {
            ATOMIC_ADD_F32(&degL1[gr], w);
            atomicAdd(&cnt[gr], 1);
        }
    }
}

// ================= scan (cnt -> start exclusive prefix) =================

__global__ __launch_bounds__(512) void scan1_k(const int* __restrict__ in,
                                               int* __restrict__ out,
                                               int* __restrict__ partials, int n) {
    __shared__ int a[1024], b[1024];
    int t = threadIdx.x;
    int base = blockIdx.x * 1024;
    a[t]       = (base + t       < n) ? in[base + t]       : 0;
    a[t + 512] = (base + t + 512 < n) ? in[base + t + 512] : 0;
    __syncthreads();
    int* src = a; int* dst = b;
    for (int off = 1; off < 1024; off <<= 1) {
        #pragma unroll
        for (int q = 0; q < 2; q++) {
            int i = t + q * 512;
            int v = src[i];
            if (i >= off) v += src[i - off];
            dst[i] = v;
        }
        __syncthreads();
        int* tmp = src; src = dst; dst = tmp;
    }
    for (int q = 0; q < 2; q++) {
        int i = t + q * 512;
        if (base + i < n) out[base + i] = i ? src[i - 1] : 0;
    }
    if (t == 0) partials[blockIdx.x] = src[1023];
}

__global__ __launch_bounds__(256) void scan2_k(int* __restrict__ partials, int m) {
    __shared__ int a[256], b[256];
    int t = threadIdx.x;
    a[t] = (t < m) ? partials[t] : 0;
    __syncthreads();
    int* src = a; int* dst = b;
    for (int off = 1; off < 256; off <<= 1) {
        int v = src[t];
        if (t >= off) v += src[t - off];
        dst[t] = v;
        __syncthreads();
        int* tmp = src; src = dst; dst = tmp;
    }
    if (t < m) partials[t] = t ? src[t - 1] : 0;
}

__global__ void scan3_k(int* __restrict__ start, int* __restrict__ next,
                        const int* __restrict__ partials,
                        const int* __restrict__ cnt, int n) {
    int i = blockIdx.x * 256 + threadIdx.x;
    if (i < n) {
        int v = start[i] + partials[i >> 10];
        start[i] = v;
        next[i] = v;
        if (i == n - 1) start[n] = v + cnt[i];
    }
}

// ===== scatter alive edges into CSR: acw = {col, w * dinv1[col]} =====

__global__ void scatter_alive_k(const int* __restrict__ r1, const int* __restrict__ c1,
                                const int* __restrict__ r2, const int* __restrict__ c2,
                                const float* __restrict__ ews,
                                const float* __restrict__ degL1,
                                int* __restrict__ next, int2* __restrict__ acw) {
    int e = blockIdx.x * 256 + threadIdx.x;
    float w = ews[e];
    if (w == 0.0f) return;
    int gr, c, sb;
    if (e < EE) { gr = r1[e]; c = c1[e]; sb = 0; }
    else        { gr = NN + r2[e - EE]; c = c2[e - EE]; sb = NN; }
    int pos = atomicAdd(&next[gr], 1);
    int2 rec;
    rec.x = c;
    rec.y = __float_as_int(w * rsqrtf(degL1[sb + c]));
    acw[pos] = rec;
}

// ================= GEMM: [n,128] x [128,128] -> [n,128] =================

__global__ __launch_bounds__(256) void gemm_nh_k(const float* __restrict__ A,
                                                 const float* __restrict__ W,
                                                 float* __restrict__ C, int n) {
    __shared__ float Ws[64 * 128];
    __shared__ float Xs[32 * 64];
    int tid = threadIdx.x;
    int row0 = blockIdx.x * 32;
    int cg = tid & 31;
    int rl = tid >> 5;
    float4 acc[4];
    #pragma unroll
    for (int i = 0; i < 4; i++) acc[i] = make_float4(0.f, 0.f, 0.f, 0.f);

    for (int kt = 0; kt < 2; kt++) {
        const float4* Wg = reinterpret_cast<const float4*>(W + kt * 64 * 128);
        float4* Ws4 = reinterpret_cast<float4*>(Ws);
        #pragma unroll
        for (int i = 0; i < 8; i++) Ws4[tid + 256 * i] = Wg[tid + 256 * i];
        float4* Xs4 = reinterpret_cast<float4*>(Xs);
        #pragma unroll
        for (int i = 0; i < 2; i++) {
            int idx = tid + 256 * i;
            int rr = idx >> 4, kq = idx & 15;
            int grow = row0 + rr; if (grow >= n) grow = n - 1;
            Xs4[idx] = reinterpret_cast<const float4*>(A + (size_t)grow * 128 + kt * 64)[kq];
        }
        __syncthreads();
        for (int k = 0; k < 64; k++) {
            float4 wv = reinterpret_cast<const float4*>(Ws + k * 128)[cg];
            #pragma unroll
            for (int r4 = 0; r4 < 4; r4++) {
                float xv = Xs[(rl + 8 * r4) * 64 + k];
                acc[r4].x += xv * wv.x; acc[r4].y += xv * wv.y;
                acc[r4].z += xv * wv.z; acc[r4].w += xv * wv.w;
            }
        }
        __syncthreads();
    }
    #pragma unroll
    for (int r4 = 0; r4 < 4; r4++) {
        int grow = row0 + rl + 8 * r4;
        if (grow < n) reinterpret_cast<float4*>(C + (size_t)grow * 128)[cg] = acc[r4];
    }
}

// ================= GEMM: [n,128] x [128,40] -> [n,40] =================

__global__ __launch_bounds__(256) void gemm_nc_k(const float* __restrict__ A,
                                                 const float* __restrict__ W,
                                                 float* __restrict__ C, int n) {
    __shared__ float Ws[128 * 40];
    __shared__ float Xs[64 * 130];
    int tid = threadIdx.x;
    int row0 = blockIdx.x * 64;
    for (int i = tid; i < 128 * 40; i += 256) Ws[i] = W[i];
    #pragma unroll
    for (int i = 0; i < 8; i++) {
        int idx = tid + 256 * i;
        int rr = idx >> 5, kq = idx & 31;
        int grow = row0 + rr; if (grow >= n) grow = n - 1;
        float4 v = reinterpret_cast<const float4*>(A + (size_t)grow * 128)[kq];
        float* dst = &Xs[rr * 130 + kq * 4];
        dst[0] = v.x; dst[1] = v.y; dst[2] = v.z; dst[3] = v.w;
    }
    __syncthreads();
    int c5 = tid & 7;
    int r  = tid >> 3;
    float acc0[5] = {0, 0, 0, 0, 0}, acc1[5] = {0, 0, 0, 0, 0};
    for (int k = 0; k < 128; k++) {
        float x0 = Xs[r * 130 + k], x1 = Xs[(r + 32) * 130 + k];
        #pragma unroll
        for (int c = 0; c < 5; c++) {
            float wv = Ws[k * 40 + c5 * 5 + c];
            acc0[c] += x0 * wv; acc1[c] += x1 * wv;
        }
    }
    int g0 = row0 + r, g1 = row0 + r + 32;
    if (g0 < n) {
        for (int c = 0; c < 5; c++) C[(size_t)g0 * 40 + c5 * 5 + c] = acc0[c];
    }
    if (g1 < n) {
        for (int c = 0; c < 5; c++) C[(size_t)g1 * 40 + c5 * 5 + c] = acc1[c];
    }
}

// ===== CSR (alive-only) aggregate D=128, fused finish+relu+norm+degL2=1 =====
// one wave per destination row (2NN rows)

__global__ __launch_bounds__(256) void agg128_fused_k(
        const float* __restrict__ h, const int* __restrict__ start,
        const int2* __restrict__ acw, const float* __restrict__ degL1,
        const float* __restrict__ bias, float* __restrict__ agg,
        float* __restrict__ norms_l2, float* __restrict__ degL2) {
    int gr = blockIdx.x * 4 + (threadIdx.x >> 6);
    int lane = threadIdx.x & 63;
    int rnode = (gr < NN) ? gr : gr - NN;
    int j0 = start[gr], j1 = start[gr + 1];
    float2 acc = make_float2(0.f, 0.f);
    for (int j = j0; j < j1; j++) {
        int2 rec = acw[j];
        float wv = __int_as_float(rec.y);
        float2 hv = reinterpret_cast<const float2*>(h)[(size_t)rec.x * 64 + lane];
        acc.x += hv.x * wv;
        acc.y += hv.y * wv;
    }
    float dr = rsqrtf(degL1[gr]);
    float2 hs = reinterpret_cast<const float2*>(h)[(size_t)rnode * 64 + lane];
    float2 bb = reinterpret_cast<const float2*>(bias)[lane];
    float vx = fmaxf(acc.x * dr + hs.x * dr * dr + bb.x, 0.0f);
    float vy = fmaxf(acc.y * dr + hs.y * dr * dr + bb.y, 0.0f);
    reinterpret_cast<float2*>(agg)[(size_t)gr * 64 + lane] = make_float2(vx, vy);
    float ss = vx * vx + vy * vy;
    #pragma unroll
    for (int off = 32; off; off >>= 1) ss += __shfl_xor(ss, off);
    if (lane == 0) {
        norms_l2[gr] = fmaxf(sqrtf(ss), EPSV);
        degL2[gr] = 1.0f;
    }
}

// ===== pass-2 edge sim: wave per row over alive CSR, all f32, no atomics =====
// row vector held in registers; updates acw.w in place; degL2 = 1 + sum (plain store)

__global__ __launch_bounds__(256) void edge_sim2_k(
        const float* __restrict__ agg, const float* __restrict__ norms_l2,
        const int* __restrict__ start, int2* __restrict__ acw,
        float* __restrict__ degL2) {
    int gr = blockIdx.x * 4 + (threadIdx.x >> 6);
    int lane = threadIdx.x & 63;
    int j0 = start[gr], j1 = start[gr + 1];
    if (j0 == j1) return;
    int set_base = (gr < NN) ? 0 : NN;
    float2 a = reinterpret_cast<const float2*>(agg)[(size_t)gr * 64 + lane];
    float nr = norms_l2[gr];
    float sum = 0.f;
    for (int j = j0; j < j1; j++) {
        int2 rec = acw[j];
        int cg = set_base + rec.x;
        float2 b = reinterpret_cast<const float2*>(agg)[(size_t)cg * 64 + lane];
        float d = a.x * b.x + a.y * b.y;
        #pragma unroll
        for (int off = 32; off; off >>= 1) d += __shfl_xor(d, off);
        float sim = d / (nr * norms_l2[cg]);
        float w2 = (sim >= THRV) ? sim : 0.0f;
        if (lane == 0) acw[j].y = __float_as_int(w2);
        sum += w2;
    }
    if (lane == 0) degL2[gr] = 1.0f + sum;
}

// ===== CSR (alive-only) aggregate D=40, fused finish =====

__global__ __launch_bounds__(256) void agg40_fused_k(
        const float* __restrict__ h2, const int* __restrict__ start,
        const int2* __restrict__ acw, const float* __restrict__ degL2,
        const float* __restrict__ bias, float* __restrict__ aggy) {
    int gr = blockIdx.x * 4 + (threadIdx.x >> 6);
    int lane = threadIdx.x & 63;
    int set_base = (gr < NN) ? 0 : NN;
    int j0 = start[gr], j1 = start[gr + 1];
    bool act = lane < 40;
    float acc = 0.f;
    for (int j = j0; j < j1; j++) {
        int2 rec = acw[j];
        float w2 = __int_as_float(rec.y);
        if (w2 == 0.0f) continue;
        int cg = set_base + rec.x;
        float nv = w2 * rsqrtf(degL2[cg]);
        if (act) acc += h2[(size_t)cg * 40 + lane] * nv;
    }
    if (act) {
        float dr = rsqrtf(degL2[gr]);
        float self = h2[(size_t)gr * 40 + lane];
        aggy[(size_t)gr * 40 + lane] = acc * dr + self * dr * dr + bias[lane];
    }
}

// ================= fusion + log_softmax =================

__global__ __launch_bounds__(256) void fusion_k(const float* __restrict__ y1,
                                                const float* __restrict__ y2,
                                                const float* __restrict__ W1,
                                                const float* __restrict__ b1,
                                                const float* __restrict__ W2,
                                                float* __restrict__ out, int n) {
    __shared__ float W1s[40 * 40];
    __shared__ float b1s[40];
    __shared__ float W2s[40];
    int tid = threadIdx.x;
    for (int i = tid; i < 1600; i += 256) W1s[i] = W1[i];
    if (tid < 40) { b1s[tid] = b1[tid]; W2s[tid] = W2[tid]; }
    __syncthreads();
    int i = blockIdx.x * 256 + tid;
    if (i >= n) return;
    float z1[40], z2[40];
    const float4* y14 = reinterpret_cast<const float4*>(y1 + (size_t)i * 40);
    const float4* y24 = reinterpret_cast<const float4*>(y2 + (size_t)i * 40);
    #pragma unroll
    for (int q = 0; q < 10; q++) {
        float4 a = y14[q], b = y24[q];
        z1[4 * q] = a.x; z1[4 * q + 1] = a.y; z1[4 * q + 2] = a.z; z1[4 * q + 3] = a.w;
        z2[4 * q] = b.x; z2[4 * q + 1] = b.y; z2[4 * q + 2] = b.z; z2[4 * q + 3] = b.w;
    }
    float w1 = 0.f, w2 = 0.f;
    for (int c = 0; c < 40; c++) {
        float s1 = b1s[c], s2 = b1s[c];
        for (int j = 0; j < 40; j++) {
            float ww = W1s[j * 40 + c];
            s1 += z1[j] * ww; s2 += z2[j] * ww;
        }
        float wa = W2s[c];
        w1 += tanhf(s1) * wa; w2 += tanhf(s2) * wa;
    }
    float m = fmaxf(w1, w2);
    float e1 = expf(w1 - m), e2 = expf(w2 - m);
    float inv = 1.0f / (e1 + e2);
    float be1 = e1 * inv, be2 = e2 * inv;
    float fu[40];
    float mx = -1e30f;
    #pragma unroll
    for (int c = 0; c < 40; c++) {
        fu[c] = be1 * z1[c] + be2 * z2[c];
        mx = fmaxf(mx, fu[c]);
    }
    float se = 0.f;
    #pragma unroll
    for (int c = 0; c < 40; c++) se += expf(fu[c] - mx);
    float ls = logf(se);
    float4* o4 = reinterpret_cast<float4*>(out + (size_t)i * 40);
    #pragma unroll
    for (int q = 0; q < 10; q++) {
        float4 v;
        v.x = fu[4 * q] - mx - ls; v.y = fu[4 * q + 1] - mx - ls;
        v.z = fu[4 * q + 2] - mx - ls; v.w = fu[4 * q + 3] - mx - ls;
        o4[q] = v;
    }
}

// ================= host =================

extern "C" void kernel_launch(void* const* d_in, const int* in_sizes, int n_in,
                              void* d_out, int out_size, void* d_ws, size_t ws_size,
                              hipStream_t stream) {
    (void)in_sizes; (void)n_in; (void)out_size; (void)ws_size;
    const float* x   = (const float*)d_in[0];
    const float* Wg1 = (const float*)d_in[1];
    const float* bg1 = (const float*)d_in[2];
    const float* Wg2 = (const float*)d_in[3];
    const float* bg2 = (const float*)d_in[4];
    const float* Wa1 = (const float*)d_in[5];
    const float* ba1 = (const float*)d_in[6];
    const float* Wa2 = (const float*)d_in[7];
    const int* ei1 = (const int*)d_in[8];
    const int* ei2 = (const int*)d_in[9];
    const int *r1 = ei1, *c1 = ei1 + EE;
    const int *r2 = ei2, *c2 = ei2 + EE;
    float* out = (float*)d_out;

    // ---- workspace carve (floats) ----
    float* ws = (float*)d_ws;
    float* norms_x  = ws;  ws += NN;
    float* norms_l2 = ws;  ws += 2 * NN;
    float* degL1    = ws;  ws += 2 * NN;
    float* degL2    = ws;  ws += 2 * NN;
    int*   cnt      = (int*)ws;  ws += 2 * NN;
    int*   start    = (int*)ws;  ws += 2 * NN + 8;
    int*   next     = (int*)ws;  ws += 2 * NN;
    int*   partials = (int*)ws;  ws += 512;
    float* ews      = ws;  ws += 2 * EE;
    int2*  acw      = (int2*)ws; ws += (size_t)2 * 2 * EE;   // worst-case all alive
    float* h        = ws;  ws += (size_t)NN * 128;           // h2 (2N x 40) overlays
    float* agg      = ws;  ws += (size_t)2 * NN * 128;       // xnb + aggy overlay
    unsigned short* xnb = (unsigned short*)agg;  // dead once pass-1 done
    float* h2   = h;
    float* aggy = agg;

    const int twoN = 2 * NN;
    const int twoE = 2 * EE;
    const int scan_blocks = (twoN + 1023) / 1024;    // 196

    // ---- pass 1: norms + sims + alive counts ----
    (void)hipMemsetAsync(cnt, 0, sizeof(int) * twoN, stream);
    normalize_k<<<NN / 4, 256, 0, stream>>>(x, xnb, norms_x, degL1);
    edge_sim1_k<<<twoE / 8, 256, 0, stream>>>(xnb, x, norms_x,
                                              r1, c1, r2, c2, ews, degL1, cnt);

    // ---- CSR over alive edges ----
    scan1_k<<<scan_blocks, 512, 0, stream>>>(cnt, start, partials, twoN);
    scan2_k<<<1, 256, 0, stream>>>(partials, scan_blocks);
    scan3_k<<<(twoN + 255) / 256, 256, 0, stream>>>(start, next, partials, cnt, twoN);
    scatter_alive_k<<<twoE / 256, 256, 0, stream>>>(r1, c1, r2, c2, ews, degL1,
                                                    next, acw);

    // ---- layer 1 ----
    gemm_nh_k<<<NN / 32, 256, 0, stream>>>(x, Wg1, h, NN);
    agg128_fused_k<<<twoN / 4, 256, 0, stream>>>(h, start, acw, degL1, bg1,
                                                 agg, norms_l2, degL2);

    // ---- layer 2 ----
    edge_sim2_k<<<twoN / 4, 256, 0, stream>>>(agg, norms_l2, start, acw, degL2);
    gemm_nc_k<<<twoN / 64, 256, 0, stream>>>(agg, Wg2, h2, twoN);
    agg40_fused_k<<<twoN / 4, 256, 0, stream>>>(h2, start, acw, degL2, bg2, aggy);

    // ---- fusion + log_softmax ----
    fusion_k<<<(NN + 255) / 256, 256, 0, stream>>>(aggy, aggy + (size_t)NN * 40,
                                                   Wa1, ba1, Wa2, out, NN);
}

// Round 6
// 472.675 us; speedup vs baseline: 1.8931x; 1.1729x over previous
//
#include <hip/hip_runtime.h>
#include <hip/hip_bf16.h>

#define NN 100000
#define EE 800000
#define THRV 0.1f
#define DELTA 0.008f
#define EPSV 1e-8f

#define ATOMIC_ADD_F32 unsafeAtomicAdd

// int8 dot4: a,b are 4 packed signed bytes; returns c + sum(a_i*b_i)
__device__ inline int dot4(int a, int b, int c) {
#if __has_builtin(__builtin_amdgcn_sdot4)
    return __builtin_amdgcn_sdot4(a, b, c, false);
#else
    int s = c;
    #pragma unroll
    for (int k = 0; k < 4; k++) {
        int av = (a << (24 - 8 * k)) >> 24;
        int bv = (b << (24 - 8 * k)) >> 24;
        s += av * bv;
    }
    return s;
#endif
}

// ======= normalize: x -> int8 rows (xq) + row scale rs + norms + degL1=1 =======
// one wave per node; lane handles 2 elements

__global__ __launch_bounds__(256) void normalize_k(const float* __restrict__ x,
                                                   unsigned short* __restrict__ xq,
                                                   float* __restrict__ rs,
                                                   float* __restrict__ norms_x,
                                                   float* __restrict__ degL1) {
    int node = blockIdx.x * 4 + (threadIdx.x >> 6);
    int lane = threadIdx.x & 63;
    float2 v = reinterpret_cast<const float2*>(x)[(size_t)node * 64 + lane];
    float ss = v.x * v.x + v.y * v.y;
    float am = fmaxf(fabsf(v.x), fabsf(v.y));
    #pragma unroll
    for (int off = 32; off; off >>= 1) {
        ss += __shfl_xor(ss, off);
        am = fmaxf(am, __shfl_xor(am, off));
    }
    float norm = fmaxf(sqrtf(ss), EPSV);
    am = fmaxf(am, 1e-12f);
    float qs = 127.0f / am;
    int q0 = __float2int_rn(v.x * qs);
    int q1 = __float2int_rn(v.y * qs);
    unsigned short packed = (unsigned short)((q0 & 0xff) | ((q1 & 0xff) << 8));
    xq[(size_t)node * 64 + lane] = packed;
    if (lane == 0) {
        norms_x[node] = norm;
        rs[node] = am / (127.0f * norm);
        degL1[node] = 1.0f;
        degL1[node + NN] = 1.0f;
    }
}

// ===== pass-1 edge sim: int8 rows, 4 edges/wave (16 lanes each), f32 fallback =====
// writes ews (per-edge), degL1 weighted atomic, cnt alive-count atomic

__global__ __launch_bounds__(256) void edge_sim1_k(
        const unsigned short* __restrict__ xq, const float* __restrict__ rs,
        const float* __restrict__ x, const float* __restrict__ norms_x,
        const int* __restrict__ r1, const int* __restrict__ c1,
        const int* __restrict__ r2, const int* __restrict__ c2,
        float* __restrict__ ews, float* __restrict__ degL1,
        int* __restrict__ cnt) {
    int tid = threadIdx.x;
    int e = blockIdx.x * 16 + (tid >> 4);            // 0..2E
    int l16 = tid & 15;
    int rnode, cnode, gr;
    if (e < EE) { rnode = r1[e]; cnode = c1[e]; gr = rnode; }
    else { int ee = e - EE; rnode = r2[ee]; cnode = c2[ee]; gr = NN + rnode; }
    int role = l16 >> 3;                              // 0: row node, 1: col node
    int j = l16 & 7;
    int node = role ? cnode : rnode;
    uint4 v = reinterpret_cast<const uint4*>(xq)[(size_t)node * 8 + j];
    uint4 p;
    p.x = (unsigned)__shfl_xor((int)v.x, 8);
    p.y = (unsigned)__shfl_xor((int)v.y, 8);
    p.z = (unsigned)__shfl_xor((int)v.z, 8);
    p.w = (unsigned)__shfl_xor((int)v.w, 8);
    int d = dot4((int)v.x, (int)p.x, 0);
    d = dot4((int)v.y, (int)p.y, d);
    d = dot4((int)v.z, (int)p.z, d);
    d = dot4((int)v.w, (int)p.w, d);
    #pragma unroll
    for (int off = 1; off < 8; off <<= 1) d += __shfl_xor(d, off);
    float sim = (float)d * rs[rnode] * rs[cnode];
    if (fabsf(sim - THRV) <= DELTA) {
        // exact f32 recompute, 16 lanes cooperate (2 chunks of each row per lane)
        const float4* xa = reinterpret_cast<const float4*>(x + (size_t)rnode * 128);
        const float4* xb = reinterpret_cast<const float4*>(x + (size_t)cnode * 128);
        float df = 0.f;
        #pragma unroll
        for (int q = 0; q < 2; q++) {
            float4 a = xa[l16 + 16 * q];
            float4 b = xb[l16 + 16 * q];
            df += a.x * b.x + a.y * b.y + a.z * b.z + a.w * b.w;
        }
        #pragma unroll
        for (int off = 1; off < 16; off <<= 1) df += __shfl_xor(df, off);
        sim = df / (norms_x[rnode] * norms_x[cnode]);
    }
    float w = (sim >= THRV) ? sim : 0.0f;
    if (l16 == 0) {
        ews[e] = w;
        if (w != 0.0f) {
            ATOMIC_ADD_F32(&degL1[gr], w);
            atomicAdd(&cnt[gr], 1);
        }
    }
}

// ================= scan (cnt -> start exclusive prefix) =================

__global__ __launch_bounds__(512) void scan1_k(const int* __restrict__ in,
                                               int* __restrict__ out,
                                               int* __restrict__ partials, int n) {
    __shared__ int a[1024], b[1024];
    int t = threadIdx.x;
    int base = blockIdx.x * 1024;
    a[t]       = (base + t       < n) ? in[base + t]       : 0;
    a[t + 512] = (base + t + 512 < n) ? in[base + t + 512] : 0;
    __syncthreads();
    int* src = a; int* dst = b;
    for (int off = 1; off < 1024; off <<= 1) {
        #pragma unroll
        for (int q = 0; q < 2; q++) {
            int i = t + q * 512;
            int v = src[i];
            if (i >= off) v += src[i - off];
            dst[i] = v;
        }
        __syncthreads();
        int* tmp = src; src = dst; dst = tmp;
    }
    for (int q = 0; q < 2; q++) {
        int i = t + q * 512;
        if (base + i < n) out[base + i] = i ? src[i - 1] : 0;
    }
    if (t == 0) partials[blockIdx.x] = src[1023];
}

__global__ __launch_bounds__(256) void scan2_k(int* __restrict__ partials, int m) {
    __shared__ int a[256], b[256];
    int t = threadIdx.x;
    a[t] = (t < m) ? partials[t] : 0;
    __syncthreads();
    int* src = a; int* dst = b;
    for (int off = 1; off < 256; off <<= 1) {
        int v = src[t];
        if (t >= off) v += src[t - off];
        dst[t] = v;
        __syncthreads();
        int* tmp = src; src = dst; dst = tmp;
    }
    if (t < m) partials[t] = t ? src[t - 1] : 0;
}

__global__ void scan3_k(int* __restrict__ start, int* __restrict__ next,
                        const int* __restrict__ partials,
                        const int* __restrict__ cnt, int n) {
    int i = blockIdx.x * 256 + threadIdx.x;
    if (i < n) {
        int v = start[i] + partials[i >> 10];
        start[i] = v;
        next[i] = v;
        if (i == n - 1) start[n] = v + cnt[i];
    }
}

// ===== scatter alive edges into CSR: acw = {col, w * dinv1[col]} =====

__global__ void scatter_alive_k(const int* __restrict__ r1, const int* __restrict__ c1,
                                const int* __restrict__ r2, const int* __restrict__ c2,
                                const float* __restrict__ ews,
                                const float* __restrict__ degL1,
                                int* __restrict__ next, int2* __restrict__ acw) {
    int e = blockIdx.x * 256 + threadIdx.x;
    float w = ews[e];
    if (w == 0.0f) return;
    int gr, c, sb;
    if (e < EE) { gr = r1[e]; c = c1[e]; sb = 0; }
    else        { gr = NN + r2[e - EE]; c = c2[e - EE]; sb = NN; }
    int pos = atomicAdd(&next[gr], 1);
    int2 rec;
    rec.x = c;
    rec.y = __float_as_int(w * rsqrtf(degL1[sb + c]));
    acw[pos] = rec;
}

// ================= GEMM: [n,128] x [128,128] -> [n,128] =================

__global__ __launch_bounds__(256) void gemm_nh_k(const float* __restrict__ A,
                                                 const float* __restrict__ W,
                                                 float* __restrict__ C, int n) {
    __shared__ float Ws[64 * 128];
    __shared__ float Xs[32 * 64];
    int tid = threadIdx.x;
    int row0 = blockIdx.x * 32;
    int cg = tid & 31;
    int rl = tid >> 5;
    float4 acc[4];
    #pragma unroll
    for (int i = 0; i < 4; i++) acc[i] = make_float4(0.f, 0.f, 0.f, 0.f);

    for (int kt = 0; kt < 2; kt++) {
        const float4* Wg = reinterpret_cast<const float4*>(W + kt * 64 * 128);
        float4* Ws4 = reinterpret_cast<float4*>(Ws);
        #pragma unroll
        for (int i = 0; i < 8; i++) Ws4[tid + 256 * i] = Wg[tid + 256 * i];
        float4* Xs4 = reinterpret_cast<float4*>(Xs);
        #pragma unroll
        for (int i = 0; i < 2; i++) {
            int idx = tid + 256 * i;
            int rr = idx >> 4, kq = idx & 15;
            int grow = row0 + rr; if (grow >= n) grow = n - 1;
            Xs4[idx] = reinterpret_cast<const float4*>(A + (size_t)grow * 128 + kt * 64)[kq];
        }
        __syncthreads();
        for (int k = 0; k < 64; k++) {
            float4 wv = reinterpret_cast<const float4*>(Ws + k * 128)[cg];
            #pragma unroll
            for (int r4 = 0; r4 < 4; r4++) {
                float xv = Xs[(rl + 8 * r4) * 64 + k];
                acc[r4].x += xv * wv.x; acc[r4].y += xv * wv.y;
                acc[r4].z += xv * wv.z; acc[r4].w += xv * wv.w;
            }
        }
        __syncthreads();
    }
    #pragma unroll
    for (int r4 = 0; r4 < 4; r4++) {
        int grow = row0 + rl + 8 * r4;
        if (grow < n) reinterpret_cast<float4*>(C + (size_t)grow * 128)[cg] = acc[r4];
    }
}

// ================= GEMM: [n,128] x [128,40] -> [n,40] =================

__global__ __launch_bounds__(256) void gemm_nc_k(const float* __restrict__ A,
                                                 const float* __restrict__ W,
                                                 float* __restrict__ C, int n) {
    __shared__ float Ws[128 * 40];
    __shared__ float Xs[64 * 130];
    int tid = threadIdx.x;
    int row0 = blockIdx.x * 64;
    for (int i = tid; i < 128 * 40; i += 256) Ws[i] = W[i];
    #pragma unroll
    for (int i = 0; i < 8; i++) {
        int idx = tid + 256 * i;
        int rr = idx >> 5, kq = idx & 31;
        int grow = row0 + rr; if (grow >= n) grow = n - 1;
        float4 v = reinterpret_cast<const float4*>(A + (size_t)grow * 128)[kq];
        float* dst = &Xs[rr * 130 + kq * 4];
        dst[0] = v.x; dst[1] = v.y; dst[2] = v.z; dst[3] = v.w;
    }
    __syncthreads();
    int c5 = tid & 7;
    int r  = tid >> 3;
    float acc0[5] = {0, 0, 0, 0, 0}, acc1[5] = {0, 0, 0, 0, 0};
    for (int k = 0; k < 128; k++) {
        float x0 = Xs[r * 130 + k], x1 = Xs[(r + 32) * 130 + k];
        #pragma unroll
        for (int c = 0; c < 5; c++) {
            float wv = Ws[k * 40 + c5 * 5 + c];
            acc0[c] += x0 * wv; acc1[c] += x1 * wv;
        }
    }
    int g0 = row0 + r, g1 = row0 + r + 32;
    if (g0 < n) {
        for (int c = 0; c < 5; c++) C[(size_t)g0 * 40 + c5 * 5 + c] = acc0[c];
    }
    if (g1 < n) {
        for (int c = 0; c < 5; c++) C[(size_t)g1 * 40 + c5 * 5 + c] = acc1[c];
    }
}

// ===== CSR (alive-only) aggregate D=128, fused finish+relu+norm+degL2=1 =====

__global__ __launch_bounds__(256) void agg128_fused_k(
        const float* __restrict__ h, const int* __restrict__ start,
        const int2* __restrict__ acw, const float* __restrict__ degL1,
        const float* __restrict__ bias, float* __restrict__ agg,
        float* __restrict__ norms_l2, float* __restrict__ degL2) {
    int gr = blockIdx.x * 4 + (threadIdx.x >> 6);
    int lane = threadIdx.x & 63;
    int rnode = (gr < NN) ? gr : gr - NN;
    int j0 = start[gr], j1 = start[gr + 1];
    float2 acc = make_float2(0.f, 0.f);
    for (int j = j0; j < j1; j++) {
        int2 rec = acw[j];
        float wv = __int_as_float(rec.y);
        float2 hv = reinterpret_cast<const float2*>(h)[(size_t)rec.x * 64 + lane];
        acc.x += hv.x * wv;
        acc.y += hv.y * wv;
    }
    float dr = rsqrtf(degL1[gr]);
    float2 hs = reinterpret_cast<const float2*>(h)[(size_t)rnode * 64 + lane];
    float2 bb = reinterpret_cast<const float2*>(bias)[lane];
    float vx = fmaxf(acc.x * dr + hs.x * dr * dr + bb.x, 0.0f);
    float vy = fmaxf(acc.y * dr + hs.y * dr * dr + bb.y, 0.0f);
    reinterpret_cast<float2*>(agg)[(size_t)gr * 64 + lane] = make_float2(vx, vy);
    float ss = vx * vx + vy * vy;
    #pragma unroll
    for (int off = 32; off; off >>= 1) ss += __shfl_xor(ss, off);
    if (lane == 0) {
        norms_l2[gr] = fmaxf(sqrtf(ss), EPSV);
        degL2[gr] = 1.0f;
    }
}

// ===== pass-2 edge sim: wave per row over alive CSR, all f32, no atomics =====

__global__ __launch_bounds__(256) void edge_sim2_k(
        const float* __restrict__ agg, const float* __restrict__ norms_l2,
        const int* __restrict__ start, int2* __restrict__ acw,
        float* __restrict__ degL2) {
    int gr = blockIdx.x * 4 + (threadIdx.x >> 6);
    int lane = threadIdx.x & 63;
    int j0 = start[gr], j1 = start[gr + 1];
    if (j0 == j1) return;
    int set_base = (gr < NN) ? 0 : NN;
    float2 a = reinterpret_cast<const float2*>(agg)[(size_t)gr * 64 + lane];
    float nr = norms_l2[gr];
    float sum = 0.f;
    for (int j = j0; j < j1; j++) {
        int2 rec = acw[j];
        int cg = set_base + rec.x;
        float2 b = reinterpret_cast<const float2*>(agg)[(size_t)cg * 64 + lane];
        float d = a.x * b.x + a.y * b.y;
        #pragma unroll
        for (int off = 32; off; off >>= 1) d += __shfl_xor(d, off);
        float sim = d / (nr * norms_l2[cg]);
        float w2 = (sim >= THRV) ? sim : 0.0f;
        if (lane == 0) acw[j].y = __float_as_int(w2);
        sum += w2;
    }
    if (lane == 0) degL2[gr] = 1.0f + sum;
}

// ===== CSR (alive-only) aggregate D=40, fused finish =====

__global__ __launch_bounds__(256) void agg40_fused_k(
        const float* __restrict__ h2, const int* __restrict__ start,
        const int2* __restrict__ acw, const float* __restrict__ degL2,
        const float* __restrict__ bias, float* __restrict__ aggy) {
    int gr = blockIdx.x * 4 + (threadIdx.x >> 6);
    int lane = threadIdx.x & 63;
    int set_base = (gr < NN) ? 0 : NN;
    int j0 = start[gr], j1 = start[gr + 1];
    bool act = lane < 40;
    float acc = 0.f;
    for (int j = j0; j < j1; j++) {
        int2 rec = acw[j];
        float w2 = __int_as_float(rec.y);
        if (w2 == 0.0f) continue;
        int cg = set_base + rec.x;
        float nv = w2 * rsqrtf(degL2[cg]);
        if (act) acc += h2[(size_t)cg * 40 + lane] * nv;
    }
    if (act) {
        float dr = rsqrtf(degL2[gr]);
        float self = h2[(size_t)gr * 40 + lane];
        aggy[(size_t)gr * 40 + lane] = acc * dr + self * dr * dr + bias[lane];
    }
}

// ================= fusion + log_softmax =================

__global__ __launch_bounds__(256) void fusion_k(const float* __restrict__ y1,
                                                const float* __restrict__ y2,
                                                const float* __restrict__ W1,
                                                const float* __restrict__ b1,
                                                const float* __restrict__ W2,
                                                float* __restrict__ out, int n) {
    __shared__ float W1s[40 * 40];
    __shared__ float b1s[40];
    __shared__ float W2s[40];
    int tid = threadIdx.x;
    for (int i = tid; i < 1600; i += 256) W1s[i] = W1[i];
    if (tid < 40) { b1s[tid] = b1[tid]; W2s[tid] = W2[tid]; }
    __syncthreads();
    int i = blockIdx.x * 256 + tid;
    if (i >= n) return;
    float z1[40], z2[40];
    const float4* y14 = reinterpret_cast<const float4*>(y1 + (size_t)i * 40);
    const float4* y24 = reinterpret_cast<const float4*>(y2 + (size_t)i * 40);
    #pragma unroll
    for (int q = 0; q < 10; q++) {
        float4 a = y14[q], b = y24[q];
        z1[4 * q] = a.x; z1[4 * q + 1] = a.y; z1[4 * q + 2] = a.z; z1[4 * q + 3] = a.w;
        z2[4 * q] = b.x; z2[4 * q + 1] = b.y; z2[4 * q + 2] = b.z; z2[4 * q + 3] = b.w;
    }
    float w1 = 0.f, w2 = 0.f;
    for (int c = 0; c < 40; c++) {
        float s1 = b1s[c], s2 = b1s[c];
        for (int j = 0; j < 40; j++) {
            float ww = W1s[j * 40 + c];
            s1 += z1[j] * ww; s2 += z2[j] * ww;
        }
        float wa = W2s[c];
        w1 += tanhf(s1) * wa; w2 += tanhf(s2) * wa;
    }
    float m = fmaxf(w1, w2);
    float e1 = expf(w1 - m), e2 = expf(w2 - m);
    float inv = 1.0f / (e1 + e2);
    float be1 = e1 * inv, be2 = e2 * inv;
    float fu[40];
    float mx = -1e30f;
    #pragma unroll
    for (int c = 0; c < 40; c++) {
        fu[c] = be1 * z1[c] + be2 * z2[c];
        mx = fmaxf(mx, fu[c]);
    }
    float se = 0.f;
    #pragma unroll
    for (int c = 0; c < 40; c++) se += expf(fu[c] - mx);
    float ls = logf(se);
    float4* o4 = reinterpret_cast<float4*>(out + (size_t)i * 40);
    #pragma unroll
    for (int q = 0; q < 10; q++) {
        float4 v;
        v.x = fu[4 * q] - mx - ls; v.y = fu[4 * q + 1] - mx - ls;
        v.z = fu[4 * q + 2] - mx - ls; v.w = fu[4 * q + 3] - mx - ls;
        o4[q] = v;
    }
}

// ================= host =================

extern "C" void kernel_launch(void* const* d_in, const int* in_sizes, int n_in,
                              void* d_out, int out_size, void* d_ws, size_t ws_size,
                              hipStream_t stream) {
    (void)in_sizes; (void)n_in; (void)out_size; (void)ws_size;
    const float* x   = (const float*)d_in[0];
    const float* Wg1 = (const float*)d_in[1];
    const float* bg1 = (const float*)d_in[2];
    const float* Wg2 = (const float*)d_in[3];
    const float* bg2 = (const float*)d_in[4];
    const float* Wa1 = (const float*)d_in[5];
    const float* ba1 = (const float*)d_in[6];
    const float* Wa2 = (const float*)d_in[7];
    const int* ei1 = (const int*)d_in[8];
    const int* ei2 = (const int*)d_in[9];
    const int *r1 = ei1, *c1 = ei1 + EE;
    const int *r2 = ei2, *c2 = ei2 + EE;
    float* out = (float*)d_out;

    // ---- workspace carve (floats) ----
    float* ws = (float*)d_ws;
    float* norms_x  = ws;  ws += NN;
    float* norms_l2 = ws;  ws += 2 * NN;
    float* rs       = ws;  ws += NN;
    float* degL1    = ws;  ws += 2 * NN;
    float* degL2    = ws;  ws += 2 * NN;
    int*   cnt      = (int*)ws;  ws += 2 * NN;
    int*   start    = (int*)ws;  ws += 2 * NN + 8;
    int*   next     = (int*)ws;  ws += 2 * NN;
    int*   partials = (int*)ws;  ws += 512;
    float* ews      = ws;  ws += 2 * EE;
    int2*  acw      = (int2*)ws; ws += (size_t)2 * 2 * EE;   // worst-case all alive
    float* h        = ws;  ws += (size_t)NN * 128;           // h2 (2N x 40) overlays
    float* agg      = ws;  ws += (size_t)2 * NN * 128;       // xq + aggy overlay
    unsigned short* xq = (unsigned short*)agg;  // int8 rows (NN x 128 bytes), dead after pass-1
    float* h2   = h;
    float* aggy = agg;

    const int twoN = 2 * NN;
    const int twoE = 2 * EE;
    const int scan_blocks = (twoN + 1023) / 1024;    // 196

    // ---- pass 1: norms + int8 quantize + sims + alive counts ----
    (void)hipMemsetAsync(cnt, 0, sizeof(int) * twoN, stream);
    normalize_k<<<NN / 4, 256, 0, stream>>>(x, xq, rs, norms_x, degL1);
    edge_sim1_k<<<twoE / 16, 256, 0, stream>>>(xq, rs, x, norms_x,
                                               r1, c1, r2, c2, ews, degL1, cnt);

    // ---- CSR over alive edges ----
    scan1_k<<<scan_blocks, 512, 0, stream>>>(cnt, start, partials, twoN);
    scan2_k<<<1, 256, 0, stream>>>(partials, scan_blocks);
    scan3_k<<<(twoN + 255) / 256, 256, 0, stream>>>(start, next, partials, cnt, twoN);
    scatter_alive_k<<<twoE / 256, 256, 0, stream>>>(r1, c1, r2, c2, ews, degL1,
                                                    next, acw);

    // ---- layer 1 ----
    gemm_nh_k<<<NN / 32, 256, 0, stream>>>(x, Wg1, h, NN);
    agg128_fused_k<<<twoN / 4, 256, 0, stream>>>(h, start, acw, degL1, bg1,
                                                 agg, norms_l2, degL2);

    // ---- layer 2 ----
    edge_sim2_k<<<twoN / 4, 256, 0, stream>>>(agg, norms_l2, start, acw, degL2);
    gemm_nc_k<<<twoN / 64, 256, 0, stream>>>(agg, Wg2, h2, twoN);
    agg40_fused_k<<<twoN / 4, 256, 0, stream>>>(h2, start, acw, degL2, bg2, aggy);

    // ---- fusion + log_softmax ----
    fusion_k<<<(NN + 255) / 256, 256, 0, stream>>>(aggy, aggy + (size_t)NN * 40,
                                                   Wa1, ba1, Wa2, out, NN);
}

// Round 7
// 468.522 us; speedup vs baseline: 1.9099x; 1.0089x over previous
//
#include <hip/hip_runtime.h>
#include <hip/hip_bf16.h>

#define NN 100000
#define EE 800000
#define THRV 0.1f
#define DELTA 0.008f
#define EPSV 1e-8f

#define ATOMIC_ADD_F32 unsafeAtomicAdd

// int8 dot4: a,b are 4 packed signed bytes; returns c + sum(a_i*b_i)
__device__ inline int dot4(int a, int b, int c) {
#if __has_builtin(__builtin_amdgcn_sdot4)
    return __builtin_amdgcn_sdot4(a, b, c, false);
#else
    int s = c;
    #pragma unroll
    for (int k = 0; k < 4; k++) {
        int av = (a << (24 - 8 * k)) >> 24;
        int bv = (b << (24 - 8 * k)) >> 24;
        s += av * bv;
    }
    return s;
#endif
}

// ======= normalize: x -> int8 rows (xq) + row scale rs + norms + degL1=1 =======

__global__ __launch_bounds__(256) void normalize_k(const float* __restrict__ x,
                                                   unsigned short* __restrict__ xq,
                                                   float* __restrict__ rs,
                                                   float* __restrict__ norms_x,
                                                   float* __restrict__ degL1) {
    int node = blockIdx.x * 4 + (threadIdx.x >> 6);
    int lane = threadIdx.x & 63;
    float2 v = reinterpret_cast<const float2*>(x)[(size_t)node * 64 + lane];
    float ss = v.x * v.x + v.y * v.y;
    float am = fmaxf(fabsf(v.x), fabsf(v.y));
    #pragma unroll
    for (int off = 32; off; off >>= 1) {
        ss += __shfl_xor(ss, off);
        am = fmaxf(am, __shfl_xor(am, off));
    }
    float norm = fmaxf(sqrtf(ss), EPSV);
    am = fmaxf(am, 1e-12f);
    float qs = 127.0f / am;
    int q0 = __float2int_rn(v.x * qs);
    int q1 = __float2int_rn(v.y * qs);
    unsigned short packed = (unsigned short)((q0 & 0xff) | ((q1 & 0xff) << 8));
    xq[(size_t)node * 64 + lane] = packed;
    if (lane == 0) {
        norms_x[node] = norm;
        rs[node] = am / (127.0f * norm);
        degL1[node] = 1.0f;
        degL1[node + NN] = 1.0f;
    }
}

// ===== pass-1 edge sim: int8 rows, 8 edges/wave (8 lanes x 32B each), f32 fallback =====

__global__ __launch_bounds__(256) void edge_sim1_k(
        const unsigned short* __restrict__ xq, const float* __restrict__ rs,
        const float* __restrict__ x, const float* __restrict__ norms_x,
        const int* __restrict__ r1, const int* __restrict__ c1,
        const int* __restrict__ r2, const int* __restrict__ c2,
        float* __restrict__ ews, float* __restrict__ degL1,
        int* __restrict__ cnt) {
    int tid = threadIdx.x;
    int e = blockIdx.x * 32 + (tid >> 3);            // 0..2E, 32 edges/block
    int q = tid & 7;
    int rnode, cnode, gr;
    if (e < EE) { rnode = r1[e]; cnode = c1[e]; gr = rnode; }
    else { int ee = e - EE; rnode = r2[ee]; cnode = c2[ee]; gr = NN + rnode; }
    int role = q >> 2;                                // 0: row node, 1: col node
    int j = q & 3;                                    // 32B chunk
    int node = role ? cnode : rnode;
    const uint4* base = reinterpret_cast<const uint4*>(xq) + (size_t)node * 8 + j * 2;
    uint4 v0 = base[0];
    uint4 v1 = base[1];
    uint4 p0, p1;
    p0.x = (unsigned)__shfl_xor((int)v0.x, 4);
    p0.y = (unsigned)__shfl_xor((int)v0.y, 4);
    p0.z = (unsigned)__shfl_xor((int)v0.z, 4);
    p0.w = (unsigned)__shfl_xor((int)v0.w, 4);
    p1.x = (unsigned)__shfl_xor((int)v1.x, 4);
    p1.y = (unsigned)__shfl_xor((int)v1.y, 4);
    p1.z = (unsigned)__shfl_xor((int)v1.z, 4);
    p1.w = (unsigned)__shfl_xor((int)v1.w, 4);
    int d = dot4((int)v0.x, (int)p0.x, 0);
    d = dot4((int)v0.y, (int)p0.y, d);
    d = dot4((int)v0.z, (int)p0.z, d);
    d = dot4((int)v0.w, (int)p0.w, d);
    d = dot4((int)v1.x, (int)p1.x, d);
    d = dot4((int)v1.y, (int)p1.y, d);
    d = dot4((int)v1.z, (int)p1.z, d);
    d = dot4((int)v1.w, (int)p1.w, d);
    d += __shfl_xor(d, 1);
    d += __shfl_xor(d, 2);
    float sim = (float)d * rs[rnode] * rs[cnode];
    if (fabsf(sim - THRV) <= DELTA) {
        // exact f32 recompute across the 8-lane group
        const float4* xa = reinterpret_cast<const float4*>(x + (size_t)rnode * 128);
        const float4* xb = reinterpret_cast<const float4*>(x + (size_t)cnode * 128);
        float df = 0.f;
        #pragma unroll
        for (int t = 0; t < 4; t++) {
            float4 a = xa[q + 8 * t];
            float4 b = xb[q + 8 * t];
            df += a.x * b.x + a.y * b.y + a.z * b.z + a.w * b.w;
        }
        df += __shfl_xor(df, 1);
        df += __shfl_xor(df, 2);
        df += __shfl_xor(df, 4);
        sim = df / (norms_x[rnode] * norms_x[cnode]);
    }
    float w = (sim >= THRV) ? sim : 0.0f;
    if (q == 0) {
        ews[e] = w;
        if (w != 0.0f) {
            ATOMIC_ADD_F32(&degL1[gr], w);
            atomicAdd(&cnt[gr], 1);
        }
    }
}

// ================= scan (cnt -> start exclusive prefix) =================

__global__ __launch_bounds__(512) void scan1_k(const int* __restrict__ in,
                                               int* __restrict__ out,
                                               int* __restrict__ partials, int n) {
    __shared__ int a[1024], b[1024];
    int t = threadIdx.x;
    int base = blockIdx.x * 1024;
    a[t]       = (base + t       < n) ? in[base + t]       : 0;
    a[t + 512] = (base + t + 512 < n) ? in[base + t + 512] : 0;
    __syncthreads();
    int* src = a; int* dst = b;
    for (int off = 1; off < 1024; off <<= 1) {
        #pragma unroll
        for (int q = 0; q < 2; q++) {
            int i = t + q * 512;
            int v = src[i];
            if (i >= off) v += src[i - off];
            dst[i] = v;
        }
        __syncthreads();
        int* tmp = src; src = dst; dst = tmp;
    }
    for (int q = 0; q < 2; q++) {
        int i = t + q * 512;
        if (base + i < n) out[base + i] = i ? src[i - 1] : 0;
    }
    if (t == 0) partials[blockIdx.x] = src[1023];
}

__global__ __launch_bounds__(256) void scan2_k(int* __restrict__ partials, int m) {
    __shared__ int a[256], b[256];
    int t = threadIdx.x;
    a[t] = (t < m) ? partials[t] : 0;
    __syncthreads();
    int* src = a; int* dst = b;
    for (int off = 1; off < 256; off <<= 1) {
        int v = src[t];
        if (t >= off) v += src[t - off];
        dst[t] = v;
        __syncthreads();
        int* tmp = src; src = dst; dst = tmp;
    }
    if (t < m) partials[t] = t ? src[t - 1] : 0;
}

__global__ void scan3_k(int* __restrict__ start, int* __restrict__ next,
                        const int* __restrict__ partials,
                        const int* __restrict__ cnt, int n) {
    int i = blockIdx.x * 256 + threadIdx.x;
    if (i < n) {
        int v = start[i] + partials[i >> 10];
        start[i] = v;
        next[i] = v;
        if (i == n - 1) start[n] = v + cnt[i];
    }
}

// ===== scatter alive edges into CSR: acw = {col, w * dinv1[col]} =====

__global__ void scatter_alive_k(const int* __restrict__ r1, const int* __restrict__ c1,
                                const int* __restrict__ r2, const int* __restrict__ c2,
                                const float* __restrict__ ews,
                                const float* __restrict__ degL1,
                                int* __restrict__ next, int2* __restrict__ acw) {
    int e = blockIdx.x * 256 + threadIdx.x;
    float w = ews[e];
    if (w == 0.0f) return;
    int gr, c, sb;
    if (e < EE) { gr = r1[e]; c = c1[e]; sb = 0; }
    else        { gr = NN + r2[e - EE]; c = c2[e - EE]; sb = NN; }
    int pos = atomicAdd(&next[gr], 1);
    int2 rec;
    rec.x = c;
    rec.y = __float_as_int(w * rsqrtf(degL1[sb + c]));
    acw[pos] = rec;
}

// ================= GEMM: [n,128] x [128,128] -> [n,128] =================

__global__ __launch_bounds__(256) void gemm_nh_k(const float* __restrict__ A,
                                                 const float* __restrict__ W,
                                                 float* __restrict__ C, int n) {
    __shared__ float Ws[64 * 128];
    __shared__ float Xs[32 * 64];
    int tid = threadIdx.x;
    int row0 = blockIdx.x * 32;
    int cg = tid & 31;
    int rl = tid >> 5;
    float4 acc[4];
    #pragma unroll
    for (int i = 0; i < 4; i++) acc[i] = make_float4(0.f, 0.f, 0.f, 0.f);

    for (int kt = 0; kt < 2; kt++) {
        const float4* Wg = reinterpret_cast<const float4*>(W + kt * 64 * 128);
        float4* Ws4 = reinterpret_cast<float4*>(Ws);
        #pragma unroll
        for (int i = 0; i < 8; i++) Ws4[tid + 256 * i] = Wg[tid + 256 * i];
        float4* Xs4 = reinterpret_cast<float4*>(Xs);
        #pragma unroll
        for (int i = 0; i < 2; i++) {
            int idx = tid + 256 * i;
            int rr = idx >> 4, kq = idx & 15;
            int grow = row0 + rr; if (grow >= n) grow = n - 1;
            Xs4[idx] = reinterpret_cast<const float4*>(A + (size_t)grow * 128 + kt * 64)[kq];
        }
        __syncthreads();
        for (int k = 0; k < 64; k++) {
            float4 wv = reinterpret_cast<const float4*>(Ws + k * 128)[cg];
            #pragma unroll
            for (int r4 = 0; r4 < 4; r4++) {
                float xv = Xs[(rl + 8 * r4) * 64 + k];
                acc[r4].x += xv * wv.x; acc[r4].y += xv * wv.y;
                acc[r4].z += xv * wv.z; acc[r4].w += xv * wv.w;
            }
        }
        __syncthreads();
    }
    #pragma unroll
    for (int r4 = 0; r4 < 4; r4++) {
        int grow = row0 + rl + 8 * r4;
        if (grow < n) reinterpret_cast<float4*>(C + (size_t)grow * 128)[cg] = acc[r4];
    }
}

// ================= GEMM: [n,128] x [128,40] -> [n,40] =================

__global__ __launch_bounds__(256) void gemm_nc_k(const float* __restrict__ A,
                                                 const float* __restrict__ W,
                                                 float* __restrict__ C, int n) {
    __shared__ float Ws[128 * 40];
    __shared__ float Xs[64 * 130];
    int tid = threadIdx.x;
    int row0 = blockIdx.x * 64;
    for (int i = tid; i < 128 * 40; i += 256) Ws[i] = W[i];
    #pragma unroll
    for (int i = 0; i < 8; i++) {
        int idx = tid + 256 * i;
        int rr = idx >> 5, kq = idx & 31;
        int grow = row0 + rr; if (grow >= n) grow = n - 1;
        float4 v = reinterpret_cast<const float4*>(A + (size_t)grow * 128)[kq];
        float* dst = &Xs[rr * 130 + kq * 4];
        dst[0] = v.x; dst[1] = v.y; dst[2] = v.z; dst[3] = v.w;
    }
    __syncthreads();
    int c5 = tid & 7;
    int r  = tid >> 3;
    float acc0[5] = {0, 0, 0, 0, 0}, acc1[5] = {0, 0, 0, 0, 0};
    for (int k = 0; k < 128; k++) {
        float x0 = Xs[r * 130 + k], x1 = Xs[(r + 32) * 130 + k];
        #pragma unroll
        for (int c = 0; c < 5; c++) {
            float wv = Ws[k * 40 + c5 * 5 + c];
            acc0[c] += x0 * wv; acc1[c] += x1 * wv;
        }
    }
    int g0 = row0 + r, g1 = row0 + r + 32;
    if (g0 < n) {
        for (int c = 0; c < 5; c++) C[(size_t)g0 * 40 + c5 * 5 + c] = acc0[c];
    }
    if (g1 < n) {
        for (int c = 0; c < 5; c++) C[(size_t)g1 * 40 + c5 * 5 + c] = acc1[c];
    }
}

// ===== CSR (alive-only) aggregate D=128, fused finish+relu+norm+degL2=1 =====
// WQ: additionally emit int8-quantized rows (xq2) + scales (rs2)

template<int WQ>
__global__ __launch_bounds__(256) void agg128_fused_k(
        const float* __restrict__ h, const int* __restrict__ start,
        const int2* __restrict__ acw, const float* __restrict__ degL1,
        const float* __restrict__ bias, float* __restrict__ agg,
        float* __restrict__ norms_l2, float* __restrict__ degL2,
        unsigned short* __restrict__ xq2, float* __restrict__ rs2) {
    int gr = blockIdx.x * 4 + (threadIdx.x >> 6);
    int lane = threadIdx.x & 63;
    int rnode = (gr < NN) ? gr : gr - NN;
    int j0 = start[gr], j1 = start[gr + 1];
    float2 acc = make_float2(0.f, 0.f);
    for (int j = j0; j < j1; j++) {
        int2 rec = acw[j];
        float wv = __int_as_float(rec.y);
        float2 hv = reinterpret_cast<const float2*>(h)[(size_t)rec.x * 64 + lane];
        acc.x += hv.x * wv;
        acc.y += hv.y * wv;
    }
    float dr = rsqrtf(degL1[gr]);
    float2 hs = reinterpret_cast<const float2*>(h)[(size_t)rnode * 64 + lane];
    float2 bb = reinterpret_cast<const float2*>(bias)[lane];
    float vx = fmaxf(acc.x * dr + hs.x * dr * dr + bb.x, 0.0f);
    float vy = fmaxf(acc.y * dr + hs.y * dr * dr + bb.y, 0.0f);
    reinterpret_cast<float2*>(agg)[(size_t)gr * 64 + lane] = make_float2(vx, vy);
    float ss = vx * vx + vy * vy;
    float am = fmaxf(vx, vy);                 // rows are non-negative (relu)
    #pragma unroll
    for (int off = 32; off; off >>= 1) {
        ss += __shfl_xor(ss, off);
        am = fmaxf(am, __shfl_xor(am, off));
    }
    float norm = fmaxf(sqrtf(ss), EPSV);
    if (WQ) {
        am = fmaxf(am, 1e-12f);
        float qs = 127.0f / am;
        int q0 = __float2int_rn(vx * qs);
        int q1 = __float2int_rn(vy * qs);
        xq2[(size_t)gr * 64 + lane] =
            (unsigned short)((q0 & 0xff) | ((q1 & 0xff) << 8));
        if (lane == 0) rs2[gr] = am / (127.0f * norm);
    }
    if (lane == 0) {
        norms_l2[gr] = norm;
        degL2[gr] = 1.0f;
    }
}

// ===== pass-2 edge sim (f32 fallback-free variant): wave per row over alive CSR =====

__global__ __launch_bounds__(256) void edge_sim2_k(
        const float* __restrict__ agg, const float* __restrict__ norms_l2,
        const int* __restrict__ start, int2* __restrict__ acw,
        float* __restrict__ degL2) {
    int gr = blockIdx.x * 4 + (threadIdx.x >> 6);
    int lane = threadIdx.x & 63;
    int j0 = start[gr], j1 = start[gr + 1];
    if (j0 == j1) return;
    int set_base = (gr < NN) ? 0 : NN;
    float2 a = reinterpret_cast<const float2*>(agg)[(size_t)gr * 64 + lane];
    float nr = norms_l2[gr];
    float sum = 0.f;
    for (int j = j0; j < j1; j++) {
        int2 rec = acw[j];
        int cg = set_base + rec.x;
        float2 b = reinterpret_cast<const float2*>(agg)[(size_t)cg * 64 + lane];
        float d = a.x * b.x + a.y * b.y;
        #pragma unroll
        for (int off = 32; off; off >>= 1) d += __shfl_xor(d, off);
        float sim = d / (nr * norms_l2[cg]);
        float w2 = (sim >= THRV) ? sim : 0.0f;
        if (lane == 0) acw[j].y = __float_as_int(w2);
        sum += w2;
    }
    if (lane == 0) degL2[gr] = 1.0f + sum;
}

// ===== pass-2 edge sim, int8 variant: 128B gathers + exact f32 fallback =====

__global__ __launch_bounds__(256) void edge_sim2_q_k(
        const unsigned short* __restrict__ xq2, const float* __restrict__ rs2,
        const float* __restrict__ agg, const float* __restrict__ norms_l2,
        const int* __restrict__ start, int2* __restrict__ acw,
        float* __restrict__ degL2) {
    int gr = blockIdx.x * 4 + (threadIdx.x >> 6);
    int lane = threadIdx.x & 63;
    int j0 = start[gr], j1 = start[gr + 1];
    if (j0 == j1) return;
    int set_base = (gr < NN) ? 0 : NN;
    unsigned int au = xq2[(size_t)gr * 64 + lane];
    int a0 = ((int)(au << 24)) >> 24;
    int a1 = ((int)(au << 16)) >> 24;
    float ra = rs2[gr];
    float nr = norms_l2[gr];
    float sum = 0.f;
    for (int j = j0; j < j1; j++) {
        int2 rec = acw[j];
        int cg = set_base + rec.x;
        unsigned int bu = xq2[(size_t)cg * 64 + lane];
        int b0 = ((int)(bu << 24)) >> 24;
        int b1 = ((int)(bu << 16)) >> 24;
        int d = a0 * b0 + a1 * b1;
        #pragma unroll
        for (int off = 32; off; off >>= 1) d += __shfl_xor(d, off);
        float sim = (float)d * ra * rs2[cg];
        if (fabsf(sim - THRV) <= DELTA) {
            float2 a = reinterpret_cast<const float2*>(agg)[(size_t)gr * 64 + lane];
            float2 b = reinterpret_cast<const float2*>(agg)[(size_t)cg * 64 + lane];
            float df = a.x * b.x + a.y * b.y;
            #pragma unroll
            for (int off = 32; off; off >>= 1) df += __shfl_xor(df, off);
            sim = df / (nr * norms_l2[cg]);
        }
        float w2 = (sim >= THRV) ? sim : 0.0f;
        if (lane == 0) acw[j].y = __float_as_int(w2);
        sum += w2;
    }
    if (lane == 0) degL2[gr] = 1.0f + sum;
}

// ===== CSR (alive-only) aggregate D=40, fused finish =====

__global__ __launch_bounds__(256) void agg40_fused_k(
        const float* __restrict__ h2, const int* __restrict__ start,
        const int2* __restrict__ acw, const float* __restrict__ degL2,
        const float* __restrict__ bias, float* __restrict__ aggy) {
    int gr = blockIdx.x * 4 + (threadIdx.x >> 6);
    int lane = threadIdx.x & 63;
    int set_base = (gr < NN) ? 0 : NN;
    int j0 = start[gr], j1 = start[gr + 1];
    bool act = lane < 40;
    float acc = 0.f;
    for (int j = j0; j < j1; j++) {
        int2 rec = acw[j];
        float w2 = __int_as_float(rec.y);
        if (w2 == 0.0f) continue;
        int cg = set_base + rec.x;
        float nv = w2 * rsqrtf(degL2[cg]);
        if (act) acc += h2[(size_t)cg * 40 + lane] * nv;
    }
    if (act) {
        float dr = rsqrtf(degL2[gr]);
        float self = h2[(size_t)gr * 40 + lane];
        aggy[(size_t)gr * 40 + lane] = acc * dr + self * dr * dr + bias[lane];
    }
}

// ================= fusion + log_softmax =================

__global__ __launch_bounds__(256) void fusion_k(const float* __restrict__ y1,
                                                const float* __restrict__ y2,
                                                const float* __restrict__ W1,
                                                const float* __restrict__ b1,
                                                const float* __restrict__ W2,
                                                float* __restrict__ out, int n) {
    __shared__ float W1s[40 * 40];
    __shared__ float b1s[40];
    __shared__ float W2s[40];
    int tid = threadIdx.x;
    for (int i = tid; i < 1600; i += 256) W1s[i] = W1[i];
    if (tid < 40) { b1s[tid] = b1[tid]; W2s[tid] = W2[tid]; }
    __syncthreads();
    int i = blockIdx.x * 256 + tid;
    if (i >= n) return;
    float z1[40], z2[40];
    const float4* y14 = reinterpret_cast<const float4*>(y1 + (size_t)i * 40);
    const float4* y24 = reinterpret_cast<const float4*>(y2 + (size_t)i * 40);
    #pragma unroll
    for (int q = 0; q < 10; q++) {
        float4 a = y14[q], b = y24[q];
        z1[4 * q] = a.x; z1[4 * q + 1] = a.y; z1[4 * q + 2] = a.z; z1[4 * q + 3] = a.w;
        z2[4 * q] = b.x; z2[4 * q + 1] = b.y; z2[4 * q + 2] = b.z; z2[4 * q + 3] = b.w;
    }
    float w1 = 0.f, w2 = 0.f;
    for (int c = 0; c < 40; c++) {
        float s1 = b1s[c], s2 = b1s[c];
        for (int j = 0; j < 40; j++) {
            float ww = W1s[j * 40 + c];
            s1 += z1[j] * ww; s2 += z2[j] * ww;
        }
        float wa = W2s[c];
        w1 += tanhf(s1) * wa; w2 += tanhf(s2) * wa;
    }
    float m = fmaxf(w1, w2);
    float e1 = expf(w1 - m), e2 = expf(w2 - m);
    float inv = 1.0f / (e1 + e2);
    float be1 = e1 * inv, be2 = e2 * inv;
    float fu[40];
    float mx = -1e30f;
    #pragma unroll
    for (int c = 0; c < 40; c++) {
        fu[c] = be1 * z1[c] + be2 * z2[c];
        mx = fmaxf(mx, fu[c]);
    }
    float se = 0.f;
    #pragma unroll
    for (int c = 0; c < 40; c++) se += expf(fu[c] - mx);
    float ls = logf(se);
    float4* o4 = reinterpret_cast<float4*>(out + (size_t)i * 40);
    #pragma unroll
    for (int q = 0; q < 10; q++) {
        float4 v;
        v.x = fu[4 * q] - mx - ls; v.y = fu[4 * q + 1] - mx - ls;
        v.z = fu[4 * q + 2] - mx - ls; v.w = fu[4 * q + 3] - mx - ls;
        o4[q] = v;
    }
}

// ================= host =================

extern "C" void kernel_launch(void* const* d_in, const int* in_sizes, int n_in,
                              void* d_out, int out_size, void* d_ws, size_t ws_size,
                              hipStream_t stream) {
    (void)in_sizes; (void)n_in; (void)out_size;
    const float* x   = (const float*)d_in[0];
    const float* Wg1 = (const float*)d_in[1];
    const float* bg1 = (const float*)d_in[2];
    const float* Wg2 = (const float*)d_in[3];
    const float* bg2 = (const float*)d_in[4];
    const float* Wa1 = (const float*)d_in[5];
    const float* ba1 = (const float*)d_in[6];
    const float* Wa2 = (const float*)d_in[7];
    const int* ei1 = (const int*)d_in[8];
    const int* ei2 = (const int*)d_in[9];
    const int *r1 = ei1, *c1 = ei1 + EE;
    const int *r2 = ei2, *c2 = ei2 + EE;
    float* out = (float*)d_out;

    // ---- workspace carve (floats) ----
    float* wp = (float*)d_ws;
    float* norms_x  = wp;  wp += NN;
    float* norms_l2 = wp;  wp += 2 * NN;
    float* rs       = wp;  wp += NN;
    float* degL1    = wp;  wp += 2 * NN;
    float* degL2    = wp;  wp += 2 * NN;
    int*   cnt      = (int*)wp;  wp += 2 * NN;
    int*   start    = (int*)wp;  wp += 2 * NN + 8;
    int*   next     = (int*)wp;  wp += 2 * NN;
    int*   partials = (int*)wp;  wp += 512;
    float* ews      = wp;  wp += 2 * EE;
    int2*  acw      = (int2*)wp; wp += (size_t)2 * 2 * EE;   // 2E int2 worst-case
    float* h        = wp;  wp += (size_t)NN * 128;           // h2 (2N x 40) overlays
    float* agg      = wp;  wp += (size_t)2 * NN * 128;       // xq + aggy overlay
    // optional q-path extension (placed at end so common layout is identical)
    float* rs2            = wp;  // 2N floats
    unsigned short* xq2   = (unsigned short*)(wp + 2 * NN);  // 2N rows x 128 B
    size_t bytes_q = ((size_t)(wp - (float*)d_ws) + 2 * NN + (size_t)2 * NN * 32)
                     * sizeof(float);
    bool useq = ws_size >= bytes_q;

    unsigned short* xq = (unsigned short*)agg;  // int8 x rows, dead after pass-1
    float* h2   = h;
    float* aggy = agg;

    const int twoN = 2 * NN;
    const int twoE = 2 * EE;
    const int scan_blocks = (twoN + 1023) / 1024;    // 196

    // ---- pass 1: norms + int8 quantize + sims + alive counts ----
    (void)hipMemsetAsync(cnt, 0, sizeof(int) * twoN, stream);
    normalize_k<<<NN / 4, 256, 0, stream>>>(x, xq, rs, norms_x, degL1);
    edge_sim1_k<<<twoE / 32, 256, 0, stream>>>(xq, rs, x, norms_x,
                                               r1, c1, r2, c2, ews, degL1, cnt);

    // ---- CSR over alive edges ----
    scan1_k<<<scan_blocks, 512, 0, stream>>>(cnt, start, partials, twoN);
    scan2_k<<<1, 256, 0, stream>>>(partials, scan_blocks);
    scan3_k<<<(twoN + 255) / 256, 256, 0, stream>>>(start, next, partials, cnt, twoN);
    scatter_alive_k<<<twoE / 256, 256, 0, stream>>>(r1, c1, r2, c2, ews, degL1,
                                                    next, acw);

    // ---- layer 1 ----
    gemm_nh_k<<<NN / 32, 256, 0, stream>>>(x, Wg1, h, NN);
    if (useq) {
        agg128_fused_k<1><<<twoN / 4, 256, 0, stream>>>(h, start, acw, degL1, bg1,
                                                        agg, norms_l2, degL2, xq2, rs2);
    } else {
        agg128_fused_k<0><<<twoN / 4, 256, 0, stream>>>(h, start, acw, degL1, bg1,
                                                        agg, norms_l2, degL2,
                                                        nullptr, nullptr);
    }

    // ---- layer 2 ----
    if (useq) {
        edge_sim2_q_k<<<twoN / 4, 256, 0, stream>>>(xq2, rs2, agg, norms_l2,
                                                    start, acw, degL2);
    } else {
        edge_sim2_k<<<twoN / 4, 256, 0, stream>>>(agg, norms_l2, start, acw, degL2);
    }
    gemm_nc_k<<<twoN / 64, 256, 0, stream>>>(agg, Wg2, h2, twoN);
    agg40_fused_k<<<twoN / 4, 256, 0, stream>>>(h2, start, acw, degL2, bg2, aggy);

    // ---- fusion + log_softmax ----
    fusion_k<<<(NN + 255) / 256, 256, 0, stream>>>(aggy, aggy + (size_t)NN * 40,
                                                   Wa1, ba1, Wa2, out, NN);
}

// Round 8
// 461.654 us; speedup vs baseline: 1.9383x; 1.0149x over previous
//
#include <hip/hip_runtime.h>
#include <hip/hip_bf16.h>

#define NN 100000
#define EE 800000
#define THRV 0.1f
#define DELTA 0.008f
#define EPSV 1e-8f

#define ATOMIC_ADD_F32 unsafeAtomicAdd

// int8 dot4
__device__ inline int dot4(int a, int b, int c) {
#if __has_builtin(__builtin_amdgcn_sdot4)
    return __builtin_amdgcn_sdot4(a, b, c, false);
#else
    int s = c;
    #pragma unroll
    for (int k = 0; k < 4; k++) {
        int av = (a << (24 - 8 * k)) >> 24;
        int bv = (b << (24 - 8 * k)) >> 24;
        s += av * bv;
    }
    return s;
#endif
}

__device__ inline unsigned short f2bf(float f) {
    unsigned int u = __float_as_uint(f);
    u += 0x7fffu + ((u >> 16) & 1u);
    return (unsigned short)(u >> 16);
}

__device__ inline float bf2f(unsigned short s) {
    return __uint_as_float(((unsigned int)s) << 16);
}

// ======= normalize: x -> int8 rows (xq) + row scale rs + norms + degL1=1 =======

__global__ __launch_bounds__(256) void normalize_k(const float* __restrict__ x,
                                                   unsigned short* __restrict__ xq,
                                                   float* __restrict__ rs,
                                                   float* __restrict__ norms_x,
                                                   float* __restrict__ degL1) {
    int node = blockIdx.x * 4 + (threadIdx.x >> 6);
    int lane = threadIdx.x & 63;
    float2 v = reinterpret_cast<const float2*>(x)[(size_t)node * 64 + lane];
    float ss = v.x * v.x + v.y * v.y;
    float am = fmaxf(fabsf(v.x), fabsf(v.y));
    #pragma unroll
    for (int off = 32; off; off >>= 1) {
        ss += __shfl_xor(ss, off);
        am = fmaxf(am, __shfl_xor(am, off));
    }
    float norm = fmaxf(sqrtf(ss), EPSV);
    am = fmaxf(am, 1e-12f);
    float qs = 127.0f / am;
    int q0 = __float2int_rn(v.x * qs);
    int q1 = __float2int_rn(v.y * qs);
    unsigned short packed = (unsigned short)((q0 & 0xff) | ((q1 & 0xff) << 8));
    xq[(size_t)node * 64 + lane] = packed;
    if (lane == 0) {
        norms_x[node] = norm;
        rs[node] = am / (127.0f * norm);
        degL1[node] = 1.0f;
        degL1[node + NN] = 1.0f;
    }
}

// ===== pass-1 edge sim: int8 rows, 8 edges/wave (8 lanes x 32B each), f32 fallback =====

__global__ __launch_bounds__(256) void edge_sim1_k(
        const unsigned short* __restrict__ xq, const float* __restrict__ rs,
        const float* __restrict__ x, const float* __restrict__ norms_x,
        const int* __restrict__ r1, const int* __restrict__ c1,
        const int* __restrict__ r2, const int* __restrict__ c2,
        float* __restrict__ ews, float* __restrict__ degL1,
        int* __restrict__ cnt) {
    int tid = threadIdx.x;
    int e = blockIdx.x * 32 + (tid >> 3);            // 0..2E, 32 edges/block
    int q = tid & 7;
    int rnode, cnode, gr;
    if (e < EE) { rnode = r1[e]; cnode = c1[e]; gr = rnode; }
    else { int ee = e - EE; rnode = r2[ee]; cnode = c2[ee]; gr = NN + rnode; }
    int role = q >> 2;                                // 0: row node, 1: col node
    int j = q & 3;                                    // 32B chunk
    int node = role ? cnode : rnode;
    const uint4* base = reinterpret_cast<const uint4*>(xq) + (size_t)node * 8 + j * 2;
    uint4 v0 = base[0];
    uint4 v1 = base[1];
    uint4 p0, p1;
    p0.x = (unsigned)__shfl_xor((int)v0.x, 4);
    p0.y = (unsigned)__shfl_xor((int)v0.y, 4);
    p0.z = (unsigned)__shfl_xor((int)v0.z, 4);
    p0.w = (unsigned)__shfl_xor((int)v0.w, 4);
    p1.x = (unsigned)__shfl_xor((int)v1.x, 4);
    p1.y = (unsigned)__shfl_xor((int)v1.y, 4);
    p1.z = (unsigned)__shfl_xor((int)v1.z, 4);
    p1.w = (unsigned)__shfl_xor((int)v1.w, 4);
    int d = dot4((int)v0.x, (int)p0.x, 0);
    d = dot4((int)v0.y, (int)p0.y, d);
    d = dot4((int)v0.z, (int)p0.z, d);
    d = dot4((int)v0.w, (int)p0.w, d);
    d = dot4((int)v1.x, (int)p1.x, d);
    d = dot4((int)v1.y, (int)p1.y, d);
    d = dot4((int)v1.z, (int)p1.z, d);
    d = dot4((int)v1.w, (int)p1.w, d);
    d += __shfl_xor(d, 1);
    d += __shfl_xor(d, 2);
    float sim = (float)d * rs[rnode] * rs[cnode];
    if (fabsf(sim - THRV) <= DELTA) {
        const float4* xa = reinterpret_cast<const float4*>(x + (size_t)rnode * 128);
        const float4* xb = reinterpret_cast<const float4*>(x + (size_t)cnode * 128);
        float df = 0.f;
        #pragma unroll
        for (int t = 0; t < 4; t++) {
            float4 a = xa[q + 8 * t];
            float4 b = xb[q + 8 * t];
            df += a.x * b.x + a.y * b.y + a.z * b.z + a.w * b.w;
        }
        df += __shfl_xor(df, 1);
        df += __shfl_xor(df, 2);
        df += __shfl_xor(df, 4);
        sim = df / (norms_x[rnode] * norms_x[cnode]);
    }
    float w = (sim >= THRV) ? sim : 0.0f;
    if (q == 0) {
        ews[e] = w;
        if (w != 0.0f) {
            ATOMIC_ADD_F32(&degL1[gr], w);
            atomicAdd(&cnt[gr], 1);
        }
    }
}

// ================= scan (cnt -> start exclusive prefix) =================

__global__ __launch_bounds__(512) void scan1_k(const int* __restrict__ in,
                                               int* __restrict__ out,
                                               int* __restrict__ partials, int n) {
    __shared__ int a[1024], b[1024];
    int t = threadIdx.x;
    int base = blockIdx.x * 1024;
    a[t]       = (base + t       < n) ? in[base + t]       : 0;
    a[t + 512] = (base + t + 512 < n) ? in[base + t + 512] : 0;
    __syncthreads();
    int* src = a; int* dst = b;
    for (int off = 1; off < 1024; off <<= 1) {
        #pragma unroll
        for (int q = 0; q < 2; q++) {
            int i = t + q * 512;
            int v = src[i];
            if (i >= off) v += src[i - off];
            dst[i] = v;
        }
        __syncthreads();
        int* tmp = src; src = dst; dst = tmp;
    }
    for (int q = 0; q < 2; q++) {
        int i = t + q * 512;
        if (base + i < n) out[base + i] = i ? src[i - 1] : 0;
    }
    if (t == 0) partials[blockIdx.x] = src[1023];
}

__global__ __launch_bounds__(256) void scan2_k(int* __restrict__ partials, int m) {
    __shared__ int a[256], b[256];
    int t = threadIdx.x;
    a[t] = (t < m) ? partials[t] : 0;
    __syncthreads();
    int* src = a; int* dst = b;
    for (int off = 1; off < 256; off <<= 1) {
        int v = src[t];
        if (t >= off) v += src[t - off];
        dst[t] = v;
        __syncthreads();
        int* tmp = src; src = dst; dst = tmp;
    }
    if (t < m) partials[t] = t ? src[t - 1] : 0;
}

__global__ void scan3_k(int* __restrict__ start, int* __restrict__ next,
                        const int* __restrict__ partials,
                        const int* __restrict__ cnt, int n) {
    int i = blockIdx.x * 256 + threadIdx.x;
    if (i < n) {
        int v = start[i] + partials[i >> 10];
        start[i] = v;
        next[i] = v;
        if (i == n - 1) start[n] = v + cnt[i];
    }
}

// ===== scatter alive edges into CSR: acw = {col, w * dinv1[col]} =====

__global__ void scatter_alive_k(const int* __restrict__ r1, const int* __restrict__ c1,
                                const int* __restrict__ r2, const int* __restrict__ c2,
                                const float* __restrict__ ews,
                                const float* __restrict__ degL1,
                                int* __restrict__ next, int2* __restrict__ acw) {
    int e = blockIdx.x * 256 + threadIdx.x;
    float w = ews[e];
    if (w == 0.0f) return;
    int gr, c, sb;
    if (e < EE) { gr = r1[e]; c = c1[e]; sb = 0; }
    else        { gr = NN + r2[e - EE]; c = c2[e - EE]; sb = NN; }
    int pos = atomicAdd(&next[gr], 1);
    int2 rec;
    rec.x = c;
    rec.y = __float_as_int(w * rsqrtf(degL1[sb + c]));
    acw[pos] = rec;
}

// ========== GEMM: [n,128] x [128,128] -> bf16 [n,128] ==========

__global__ __launch_bounds__(256) void gemm_nh_k(const float* __restrict__ A,
                                                 const float* __restrict__ W,
                                                 unsigned short* __restrict__ Cb, int n) {
    __shared__ float Ws[64 * 128];
    __shared__ float Xs[32 * 64];
    int tid = threadIdx.x;
    int row0 = blockIdx.x * 32;
    int cg = tid & 31;
    int rl = tid >> 5;
    float4 acc[4];
    #pragma unroll
    for (int i = 0; i < 4; i++) acc[i] = make_float4(0.f, 0.f, 0.f, 0.f);

    for (int kt = 0; kt < 2; kt++) {
        const float4* Wg = reinterpret_cast<const float4*>(W + kt * 64 * 128);
        float4* Ws4 = reinterpret_cast<float4*>(Ws);
        #pragma unroll
        for (int i = 0; i < 8; i++) Ws4[tid + 256 * i] = Wg[tid + 256 * i];
        float4* Xs4 = reinterpret_cast<float4*>(Xs);
        #pragma unroll
        for (int i = 0; i < 2; i++) {
            int idx = tid + 256 * i;
            int rr = idx >> 4, kq = idx & 15;
            int grow = row0 + rr; if (grow >= n) grow = n - 1;
            Xs4[idx] = reinterpret_cast<const float4*>(A + (size_t)grow * 128 + kt * 64)[kq];
        }
        __syncthreads();
        for (int k = 0; k < 64; k++) {
            float4 wv = reinterpret_cast<const float4*>(Ws + k * 128)[cg];
            #pragma unroll
            for (int r4 = 0; r4 < 4; r4++) {
                float xv = Xs[(rl + 8 * r4) * 64 + k];
                acc[r4].x += xv * wv.x; acc[r4].y += xv * wv.y;
                acc[r4].z += xv * wv.z; acc[r4].w += xv * wv.w;
            }
        }
        __syncthreads();
    }
    #pragma unroll
    for (int r4 = 0; r4 < 4; r4++) {
        int grow = row0 + rl + 8 * r4;
        if (grow < n) {
            ushort4 o;
            o.x = f2bf(acc[r4].x); o.y = f2bf(acc[r4].y);
            o.z = f2bf(acc[r4].z); o.w = f2bf(acc[r4].w);
            reinterpret_cast<ushort4*>(Cb + (size_t)grow * 128)[cg] = o;
        }
    }
}

// ================= GEMM: [n,128] x [128,40] -> [n,40] =================

__global__ __launch_bounds__(256) void gemm_nc_k(const float* __restrict__ A,
                                                 const float* __restrict__ W,
                                                 float* __restrict__ C, int n) {
    __shared__ float Ws[128 * 40];
    __shared__ float Xs[64 * 130];
    int tid = threadIdx.x;
    int row0 = blockIdx.x * 64;
    for (int i = tid; i < 128 * 40; i += 256) Ws[i] = W[i];
    #pragma unroll
    for (int i = 0; i < 8; i++) {
        int idx = tid + 256 * i;
        int rr = idx >> 5, kq = idx & 31;
        int grow = row0 + rr; if (grow >= n) grow = n - 1;
        float4 v = reinterpret_cast<const float4*>(A + (size_t)grow * 128)[kq];
        float* dst = &Xs[rr * 130 + kq * 4];
        dst[0] = v.x; dst[1] = v.y; dst[2] = v.z; dst[3] = v.w;
    }
    __syncthreads();
    int c5 = tid & 7;
    int r  = tid >> 3;
    float acc0[5] = {0, 0, 0, 0, 0}, acc1[5] = {0, 0, 0, 0, 0};
    for (int k = 0; k < 128; k++) {
        float x0 = Xs[r * 130 + k], x1 = Xs[(r + 32) * 130 + k];
        #pragma unroll
        for (int c = 0; c < 5; c++) {
            float wv = Ws[k * 40 + c5 * 5 + c];
            acc0[c] += x0 * wv; acc1[c] += x1 * wv;
        }
    }
    int g0 = row0 + r, g1 = row0 + r + 32;
    if (g0 < n) {
        for (int c = 0; c < 5; c++) C[(size_t)g0 * 40 + c5 * 5 + c] = acc0[c];
    }
    if (g1 < n) {
        for (int c = 0; c < 5; c++) C[(size_t)g1 * 40 + c5 * 5 + c] = acc1[c];
    }
}

// ===== CSR (alive-only) aggregate D=128 over bf16 h, fused finish+relu+norm+degL2=1 =====

__global__ __launch_bounds__(256) void agg128_fused_k(
        const unsigned short* __restrict__ hb, const int* __restrict__ start,
        const int2* __restrict__ acw, const float* __restrict__ degL1,
        const float* __restrict__ bias, float* __restrict__ agg,
        float* __restrict__ norms_l2, float* __restrict__ degL2) {
    int gr = blockIdx.x * 4 + (threadIdx.x >> 6);
    int lane = threadIdx.x & 63;
    int rnode = (gr < NN) ? gr : gr - NN;
    int j0 = start[gr], j1 = start[gr + 1];
    float2 acc = make_float2(0.f, 0.f);
    for (int j = j0; j < j1; j++) {
        int2 rec = acw[j];
        float wv = __int_as_float(rec.y);
        unsigned int hv = reinterpret_cast<const unsigned int*>(hb)
                              [(size_t)rec.x * 64 + lane];
        acc.x += bf2f((unsigned short)(hv & 0xffff)) * wv;
        acc.y += bf2f((unsigned short)(hv >> 16)) * wv;
    }
    float dr = rsqrtf(degL1[gr]);
    unsigned int hs = reinterpret_cast<const unsigned int*>(hb)
                          [(size_t)rnode * 64 + lane];
    float hx = bf2f((unsigned short)(hs & 0xffff));
    float hy = bf2f((unsigned short)(hs >> 16));
    float2 bb = reinterpret_cast<const float2*>(bias)[lane];
    float vx = fmaxf(acc.x * dr + hx * dr * dr + bb.x, 0.0f);
    float vy = fmaxf(acc.y * dr + hy * dr * dr + bb.y, 0.0f);
    reinterpret_cast<float2*>(agg)[(size_t)gr * 64 + lane] = make_float2(vx, vy);
    float ss = vx * vx + vy * vy;
    #pragma unroll
    for (int off = 32; off; off >>= 1) ss += __shfl_xor(ss, off);
    if (lane == 0) {
        norms_l2[gr] = fmaxf(sqrtf(ss), EPSV);
        degL2[gr] = 1.0f;
    }
}

// ===== pass-2 edge sim: wave per row over alive CSR, all f32, no atomics =====

__global__ __launch_bounds__(256) void edge_sim2_k(
        const float* __restrict__ agg, const float* __restrict__ norms_l2,
        const int* __restrict__ start, int2* __restrict__ acw,
        float* __restrict__ degL2) {
    int gr = blockIdx.x * 4 + (threadIdx.x >> 6);
    int lane = threadIdx.x & 63;
    int j0 = start[gr], j1 = start[gr + 1];
    if (j0 == j1) return;
    int set_base = (gr < NN) ? 0 : NN;
    float2 a = reinterpret_cast<const float2*>(agg)[(size_t)gr * 64 + lane];
    float nr = norms_l2[gr];
    float sum = 0.f;
    for (int j = j0; j < j1; j++) {
        int2 rec = acw[j];
        int cg = set_base + rec.x;
        float2 b = reinterpret_cast<const float2*>(agg)[(size_t)cg * 64 + lane];
        float d = a.x * b.x + a.y * b.y;
        #pragma unroll
        for (int off = 32; off; off >>= 1) d += __shfl_xor(d, off);
        float sim = d / (nr * norms_l2[cg]);
        float w2 = (sim >= THRV) ? sim : 0.0f;
        if (lane == 0) acw[j].y = __float_as_int(w2);
        sum += w2;
    }
    if (lane == 0) degL2[gr] = 1.0f + sum;
}

// ===== CSR (alive-only) aggregate D=40, fused finish =====

__global__ __launch_bounds__(256) void agg40_fused_k(
        const float* __restrict__ h2, const int* __restrict__ start,
        const int2* __restrict__ acw, const float* __restrict__ degL2,
        const float* __restrict__ bias, float* __restrict__ aggy) {
    int gr = blockIdx.x * 4 + (threadIdx.x >> 6);
    int lane = threadIdx.x & 63;
    int set_base = (gr < NN) ? 0 : NN;
    int j0 = start[gr], j1 = start[gr + 1];
    bool act = lane < 40;
    float acc = 0.f;
    for (int j = j0; j < j1; j++) {
        int2 rec = acw[j];
        float w2 = __int_as_float(rec.y);
        if (w2 == 0.0f) continue;
        int cg = set_base + rec.x;
        float nv = w2 * rsqrtf(degL2[cg]);
        if (act) acc += h2[(size_t)cg * 40 + lane] * nv;
    }
    if (act) {
        float dr = rsqrtf(degL2[gr]);
        float self = h2[(size_t)gr * 40 + lane];
        aggy[(size_t)gr * 40 + lane] = acc * dr + self * dr * dr + bias[lane];
    }
}

// ================= fusion + log_softmax =================

__global__ __launch_bounds__(256) void fusion_k(const float* __restrict__ y1,
                                                const float* __restrict__ y2,
                                                const float* __restrict__ W1,
                                                const float* __restrict__ b1,
                                                const float* __restrict__ W2,
                                                float* __restrict__ out, int n) {
    __shared__ float W1s[40 * 40];
    __shared__ float b1s[40];
    __shared__ float W2s[40];
    int tid = threadIdx.x;
    for (int i = tid; i < 1600; i += 256) W1s[i] = W1[i];
    if (tid < 40) { b1s[tid] = b1[tid]; W2s[tid] = W2[tid]; }
    __syncthreads();
    int i = blockIdx.x * 256 + tid;
    if (i >= n) return;
    float z1[40], z2[40];
    const float4* y14 = reinterpret_cast<const float4*>(y1 + (size_t)i * 40);
    const float4* y24 = reinterpret_cast<const float4*>(y2 + (size_t)i * 40);
    #pragma unroll
    for (int q = 0; q < 10; q++) {
        float4 a = y14[q], b = y24[q];
        z1[4 * q] = a.x; z1[4 * q + 1] = a.y; z1[4 * q + 2] = a.z; z1[4 * q + 3] = a.w;
        z2[4 * q] = b.x; z2[4 * q + 1] = b.y; z2[4 * q + 2] = b.z; z2[4 * q + 3] = b.w;
    }
    float w1 = 0.f, w2 = 0.f;
    for (int c = 0; c < 40; c++) {
        float s1 = b1s[c], s2 = b1s[c];
        for (int j = 0; j < 40; j++) {
            float ww = W1s[j * 40 + c];
            s1 += z1[j] * ww; s2 += z2[j] * ww;
        }
        float wa = W2s[c];
        w1 += tanhf(s1) * wa; w2 += tanhf(s2) * wa;
    }
    float m = fmaxf(w1, w2);
    float e1 = expf(w1 - m), e2 = expf(w2 - m);
    float inv = 1.0f / (e1 + e2);
    float be1 = e1 * inv, be2 = e2 * inv;
    float fu[40];
    float mx = -1e30f;
    #pragma unroll
    for (int c = 0; c < 40; c++) {
        fu[c] = be1 * z1[c] + be2 * z2[c];
        mx = fmaxf(mx, fu[c]);
    }
    float se = 0.f;
    #pragma unroll
    for (int c = 0; c < 40; c++) se += expf(fu[c] - mx);
    float ls = logf(se);
    float4* o4 = reinterpret_cast<float4*>(out + (size_t)i * 40);
    #pragma unroll
    for (int q = 0; q < 10; q++) {
        float4 v;
        v.x = fu[4 * q] - mx - ls; v.y = fu[4 * q + 1] - mx - ls;
        v.z = fu[4 * q + 2] - mx - ls; v.w = fu[4 * q + 3] - mx - ls;
        o4[q] = v;
    }
}

// ================= host =================

extern "C" void kernel_launch(void* const* d_in, const int* in_sizes, int n_in,
                              void* d_out, int out_size, void* d_ws, size_t ws_size,
                              hipStream_t stream) {
    (void)in_sizes; (void)n_in; (void)out_size; (void)ws_size;
    const float* x   = (const float*)d_in[0];
    const float* Wg1 = (const float*)d_in[1];
    const float* bg1 = (const float*)d_in[2];
    const float* Wg2 = (const float*)d_in[3];
    const float* bg2 = (const float*)d_in[4];
    const float* Wa1 = (const float*)d_in[5];
    const float* ba1 = (const float*)d_in[6];
    const float* Wa2 = (const float*)d_in[7];
    const int* ei1 = (const int*)d_in[8];
    const int* ei2 = (const int*)d_in[9];
    const int *r1 = ei1, *c1 = ei1 + EE;
    const int *r2 = ei2, *c2 = ei2 + EE;
    float* out = (float*)d_out;

    // ---- workspace carve (f32 words); total ~184.8 MB ----
    float* wp = (float*)d_ws;
    float* norms_x  = wp;  wp += NN;
    float* norms_l2 = wp;  wp += 2 * NN;
    float* rs       = wp;  wp += NN;
    float* degL1    = wp;  wp += 2 * NN;
    float* degL2    = wp;  wp += 2 * NN;
    int*   cnt      = (int*)wp;  wp += 2 * NN;
    int*   start    = (int*)wp;  wp += 2 * NN + 8;
    int*   next     = (int*)wp;  wp += 2 * NN;
    int*   partials = (int*)wp;  wp += 512;
    float* ews      = wp;  wp += 2 * EE;
    int2*  acw      = (int2*)wp; wp += (size_t)2 * 2 * EE;    // 2E records worst-case
    unsigned short* hb = (unsigned short*)wp; wp += (size_t)NN * 64;  // NN x 128 bf16
    float* h2       = wp;  wp += (size_t)2 * NN * 40;
    float* agg      = wp;  wp += (size_t)2 * NN * 128;        // xq overlays head; aggy overlays
    unsigned short* xq = (unsigned short*)agg;  // int8 x rows, dead after pass-1
    float* aggy = agg;

    const int twoN = 2 * NN;
    const int twoE = 2 * EE;
    const int scan_blocks = (twoN + 1023) / 1024;    // 196

    // ---- pass 1: norms + int8 quantize + sims + alive counts ----
    (void)hipMemsetAsync(cnt, 0, sizeof(int) * twoN, stream);
    normalize_k<<<NN / 4, 256, 0, stream>>>(x, xq, rs, norms_x, degL1);
    edge_sim1_k<<<twoE / 32, 256, 0, stream>>>(xq, rs, x, norms_x,
                                               r1, c1, r2, c2, ews, degL1, cnt);

    // ---- CSR over alive edges ----
    scan1_k<<<scan_blocks, 512, 0, stream>>>(cnt, start, partials, twoN);
    scan2_k<<<1, 256, 0, stream>>>(partials, scan_blocks);
    scan3_k<<<(twoN + 255) / 256, 256, 0, stream>>>(start, next, partials, cnt, twoN);
    scatter_alive_k<<<twoE / 256, 256, 0, stream>>>(r1, c1, r2, c2, ews, degL1,
                                                    next, acw);

    // ---- layer 1 ----
    gemm_nh_k<<<NN / 32, 256, 0, stream>>>(x, Wg1, hb, NN);
    agg128_fused_k<<<twoN / 4, 256, 0, stream>>>(hb, start, acw, degL1, bg1,
                                                 agg, norms_l2, degL2);

    // ---- layer 2 ----
    edge_sim2_k<<<twoN / 4, 256, 0, stream>>>(agg, norms_l2, start, acw, degL2);
    gemm_nc_k<<<twoN / 64, 256, 0, stream>>>(agg, Wg2, h2, twoN);
    agg40_fused_k<<<twoN / 4, 256, 0, stream>>>(h2, start, acw, degL2, bg2, aggy);

    // ---- fusion + log_softmax ----
    fusion_k<<<(NN + 255) / 256, 256, 0, stream>>>(aggy, aggy + (size_t)NN * 40,
                                                   Wa1, ba1, Wa2, out, NN);
}